// Round 1
// baseline (2973.758 us; speedup 1.0000x reference)
//
#include <hip/hip_runtime.h>

#define NN 50000
#define DD 128
#define SLOPE 0.01f

// ---------------------------------------------------------------------------
// Phase 1: H[v] += E[src[e]] for each edge. One thread per (edge, float4-chunk).
// 32 threads cooperate on one edge row (128 floats = 32 float4).
// ---------------------------------------------------------------------------
__global__ __launch_bounds__(256) void scatter_add(
    const float* __restrict__ E, const int* __restrict__ src,
    const int* __restrict__ dst, float* __restrict__ H, int n_edges)
{
    int t = blockIdx.x * 256 + threadIdx.x;
    int e = t >> 5;
    if (e >= n_edges) return;
    int c = t & 31;
    int u = src[e];
    int v = dst[e];
    float4 a = ((const float4*)E)[(size_t)u * 32 + c];
    float* hp = H + (size_t)v * DD + c * 4;
    atomicAdd(hp + 0, a.x);
    atomicAdd(hp + 1, a.y);
    atomicAdd(hp + 2, a.z);
    atomicAdd(hp + 3, a.w);
}

// ---------------------------------------------------------------------------
// Phase 2: out = leaky(H @ W1^T + b1) + leaky((E*H) @ W2^T + b2)
// Block: 32 nodes, 256 threads. Thread computes 2 columns {jg, jg+64} x 8 nodes.
// Hs/EHs staged full-row in LDS (inner reads are 2-address broadcasts -> free).
// W K-tiled (KT=16) into LDS, rows padded to 20 floats (80B, 16B-aligned; b128
// reads land on 8 disjoint 4-bank groups = the wave64 b128 hardware floor).
// ---------------------------------------------------------------------------
__global__ __launch_bounds__(256) void fused_mlp(
    const float* __restrict__ E, const float* __restrict__ H,
    const float* __restrict__ W1, const float* __restrict__ b1,
    const float* __restrict__ W2, const float* __restrict__ b2,
    float* __restrict__ out)
{
    __shared__ float Hs[32][DD];     // 16 KB
    __shared__ float EHs[32][DD];    // 16 KB
    __shared__ float W1s[DD][20];    // 10 KB (K-tile of 16, +4 pad)
    __shared__ float W2s[DD][20];    // 10 KB

    const int tid = threadIdx.x;
    const int v0 = blockIdx.x * 32;
    const int nvalid = min(32, NN - v0);

    // stage H and E*H rows for this node tile
    for (int i = 0; i < 4; ++i) {
        int f = tid + 256 * i;       // 0..1023 float4 slots
        int n = f >> 5, c = f & 31;
        float4 h = make_float4(0.f, 0.f, 0.f, 0.f);
        float4 eh = h;
        if (n < nvalid) {
            h = ((const float4*)H)[(size_t)(v0 + n) * 32 + c];
            float4 e4 = ((const float4*)E)[(size_t)(v0 + n) * 32 + c];
            eh = make_float4(e4.x * h.x, e4.y * h.y, e4.z * h.z, e4.w * h.w);
        }
        *((float4*)&Hs[n][c * 4]) = h;
        *((float4*)&EHs[n][c * 4]) = eh;
    }

    const int jg = tid & 63;   // column group: handles j = jg and jg+64
    const int n0 = (tid >> 6) * 8;

    float acc1a[8] = {}, acc1b[8] = {}, acc2a[8] = {}, acc2b[8] = {};

    for (int t8 = 0; t8 < 8; ++t8) {
        const int k0 = t8 * 16;
        __syncthreads();  // protects Hs staging (t8=0) and prior-tile W reads
        // stage W K-tile: 128x16 each, 2048 floats, 8 per thread
        for (int i = 0; i < 8; ++i) {
            int f = tid + 256 * i;
            int j = f >> 4, kk = f & 15;
            W1s[j][kk] = W1[j * DD + k0 + kk];
            W2s[j][kk] = W2[j * DD + k0 + kk];
        }
        __syncthreads();
        for (int c = 0; c < 4; ++c) {
            float4 w1a = *((const float4*)&W1s[jg][c * 4]);
            float4 w1b = *((const float4*)&W1s[jg + 64][c * 4]);
            float4 w2a = *((const float4*)&W2s[jg][c * 4]);
            float4 w2b = *((const float4*)&W2s[jg + 64][c * 4]);
            const int kk = k0 + c * 4;
            for (int n = 0; n < 8; ++n) {
                float4 h = *((const float4*)&Hs[n0 + n][kk]);
                float4 eh = *((const float4*)&EHs[n0 + n][kk]);
                acc1a[n] += h.x * w1a.x + h.y * w1a.y + h.z * w1a.z + h.w * w1a.w;
                acc1b[n] += h.x * w1b.x + h.y * w1b.y + h.z * w1b.z + h.w * w1b.w;
                acc2a[n] += eh.x * w2a.x + eh.y * w2a.y + eh.z * w2a.z + eh.w * w2a.w;
                acc2b[n] += eh.x * w2b.x + eh.y * w2b.y + eh.z * w2b.z + eh.w * w2b.w;
            }
        }
    }

    const float b1a = b1[jg], b1b = b1[jg + 64];
    const float b2a = b2[jg], b2b = b2[jg + 64];
    for (int n = 0; n < 8; ++n) {
        if (n0 + n < nvalid) {
            const int v = v0 + n0 + n;
            float x1 = acc1a[n] + b1a;
            x1 = x1 > 0.f ? x1 : SLOPE * x1;
            float x2 = acc2a[n] + b2a;
            x2 = x2 > 0.f ? x2 : SLOPE * x2;
            out[(size_t)v * DD + jg] = x1 + x2;
            float y1 = acc1b[n] + b1b;
            y1 = y1 > 0.f ? y1 : SLOPE * y1;
            float y2 = acc2b[n] + b2b;
            y2 = y2 > 0.f ? y2 : SLOPE * y2;
            out[(size_t)v * DD + jg + 64] = y1 + y2;
        }
    }
}

extern "C" void kernel_launch(void* const* d_in, const int* in_sizes, int n_in,
                              void* d_out, int out_size, void* d_ws, size_t ws_size,
                              hipStream_t stream)
{
    const float* E  = (const float*)d_in[0];
    const float* W1 = (const float*)d_in[1];
    const float* b1 = (const float*)d_in[2];
    const float* W2 = (const float*)d_in[3];
    const float* b2 = (const float*)d_in[4];
    const int* src  = (const int*)d_in[5];
    const int* dst  = (const int*)d_in[6];
    float* out = (float*)d_out;
    const int n_edges = in_sizes[5];

    const size_t hbytes = (size_t)NN * DD * sizeof(float);
    // H lives in workspace; fallback overlays on d_out (safe: each fused_mlp
    // block stages its own H rows to LDS before overwriting them).
    float* H = (ws_size >= hbytes) ? (float*)d_ws : out;

    hipMemsetAsync(H, 0, hbytes, stream);

    const int total = n_edges * 32;           // one thread per (edge, float4)
    scatter_add<<<(total + 255) / 256, 256, 0, stream>>>(E, src, dst, H, n_edges);

    fused_mlp<<<(NN + 31) / 32, 256, 0, stream>>>(E, H, W1, b1, W2, b2, out);
}

// Round 2
// 530.433 us; speedup vs baseline: 5.6063x; 5.6063x over previous
//
#include <hip/hip_runtime.h>

#define NN 50000
#define DD 128
#define SLOPE 0.01f
#define CAP 96        // max deg ~58 for Binomial(1.6M, 1/50k); 96 is >6 sigma past
#define OVCAP 8192

// ---------------------------------------------------------------------------
// Build padded per-destination source lists. 1.6M int atomics over 50k
// L2-resident counters (fast), instead of 204.8M f32 atomics on H.
// ---------------------------------------------------------------------------
__global__ __launch_bounds__(256) void place_edges(
    const int* __restrict__ src, const int* __restrict__ dst,
    int* __restrict__ cnt, int* __restrict__ lists,
    int* __restrict__ ovf_cnt, int2* __restrict__ ovf, int n_edges)
{
    int e = blockIdx.x * 256 + threadIdx.x;
    if (e >= n_edges) return;
    int v = dst[e];
    int pos = atomicAdd(&cnt[v], 1);
    if (pos < CAP) {
        lists[v * CAP + pos] = src[e];
    } else {
        int oi = atomicAdd(ovf_cnt, 1);
        if (oi < OVCAP) ovf[oi] = make_int2(src[e], v);
    }
}

// ---------------------------------------------------------------------------
// H[v] = sum_{u in list[v]} E[u].  32 threads per node (one float4 chunk each),
// 8 nodes per block. All reads hit full 512B E rows (L2/L3-resident table).
// No atomics; H written once, streaming.
// ---------------------------------------------------------------------------
__global__ __launch_bounds__(256) void gather_sum(
    const float* __restrict__ E, const int* __restrict__ cnt,
    const int* __restrict__ lists, float* __restrict__ H)
{
    int t = blockIdx.x * 256 + threadIdx.x;
    int v = t >> 5;
    if (v >= NN) return;
    int c = t & 31;
    int n = cnt[v];
    n = n < CAP ? n : CAP;
    const int* lst = lists + v * CAP;
    const float4* E4 = (const float4*)E;
    float4 acc = make_float4(0.f, 0.f, 0.f, 0.f);
    int i = 0;
    for (; i + 4 <= n; i += 4) {               // 4 loads in flight per lane
        int4 u4 = *((const int4*)(lst + i));   // lst 16B-aligned (CAP%4==0)
        float4 a = E4[(size_t)u4.x * 32 + c];
        float4 b = E4[(size_t)u4.y * 32 + c];
        float4 d = E4[(size_t)u4.z * 32 + c];
        float4 f = E4[(size_t)u4.w * 32 + c];
        acc.x += a.x + b.x + d.x + f.x;
        acc.y += a.y + b.y + d.y + f.y;
        acc.z += a.z + b.z + d.z + f.z;
        acc.w += a.w + b.w + d.w + f.w;
    }
    for (; i < n; ++i) {
        float4 a = E4[(size_t)lst[i] * 32 + c];
        acc.x += a.x; acc.y += a.y; acc.z += a.z; acc.w += a.w;
    }
    ((float4*)H)[(size_t)v * 32 + c] = acc;
}

// Overflow edges (expected: zero) applied with atomics AFTER gather overwrote H.
__global__ __launch_bounds__(256) void apply_overflow(
    const int* __restrict__ ovf_cnt, const int2* __restrict__ ovf,
    const float* __restrict__ E, float* __restrict__ H)
{
    int total = *ovf_cnt;
    total = total < OVCAP ? total : OVCAP;
    int work = total * 32;
    for (int t = blockIdx.x * 256 + threadIdx.x; t < work; t += gridDim.x * 256) {
        int i = t >> 5, c = t & 31;
        int2 edge = ovf[i];
        float4 a = ((const float4*)E)[(size_t)edge.x * 32 + c];
        float* hp = H + (size_t)edge.y * DD + c * 4;
        atomicAdd(hp + 0, a.x);
        atomicAdd(hp + 1, a.y);
        atomicAdd(hp + 2, a.z);
        atomicAdd(hp + 3, a.w);
    }
}

// Fallback path (ws too small): direct f32 atomics.
__global__ __launch_bounds__(256) void scatter_add(
    const float* __restrict__ E, const int* __restrict__ src,
    const int* __restrict__ dst, float* __restrict__ H, int n_edges)
{
    int t = blockIdx.x * 256 + threadIdx.x;
    int e = t >> 5;
    if (e >= n_edges) return;
    int c = t & 31;
    float4 a = ((const float4*)E)[(size_t)src[e] * 32 + c];
    float* hp = H + (size_t)dst[e] * DD + c * 4;
    atomicAdd(hp + 0, a.x);
    atomicAdd(hp + 1, a.y);
    atomicAdd(hp + 2, a.z);
    atomicAdd(hp + 3, a.w);
}

// ---------------------------------------------------------------------------
// Phase 2: out = leaky(H @ W1^T + b1) + leaky((E*H) @ W2^T + b2)
// ---------------------------------------------------------------------------
__global__ __launch_bounds__(256) void fused_mlp(
    const float* __restrict__ E, const float* __restrict__ H,
    const float* __restrict__ W1, const float* __restrict__ b1,
    const float* __restrict__ W2, const float* __restrict__ b2,
    float* __restrict__ out)
{
    __shared__ float Hs[32][DD];
    __shared__ float EHs[32][DD];
    __shared__ float W1s[DD][20];
    __shared__ float W2s[DD][20];

    const int tid = threadIdx.x;
    const int v0 = blockIdx.x * 32;
    const int nvalid = min(32, NN - v0);

    for (int i = 0; i < 4; ++i) {
        int f = tid + 256 * i;
        int n = f >> 5, c = f & 31;
        float4 h = make_float4(0.f, 0.f, 0.f, 0.f);
        float4 eh = h;
        if (n < nvalid) {
            h = ((const float4*)H)[(size_t)(v0 + n) * 32 + c];
            float4 e4 = ((const float4*)E)[(size_t)(v0 + n) * 32 + c];
            eh = make_float4(e4.x * h.x, e4.y * h.y, e4.z * h.z, e4.w * h.w);
        }
        *((float4*)&Hs[n][c * 4]) = h;
        *((float4*)&EHs[n][c * 4]) = eh;
    }

    const int jg = tid & 63;
    const int n0 = (tid >> 6) * 8;

    float acc1a[8] = {}, acc1b[8] = {}, acc2a[8] = {}, acc2b[8] = {};

    for (int t8 = 0; t8 < 8; ++t8) {
        const int k0 = t8 * 16;
        __syncthreads();
        for (int i = 0; i < 8; ++i) {
            int f = tid + 256 * i;
            int j = f >> 4, kk = f & 15;
            W1s[j][kk] = W1[j * DD + k0 + kk];
            W2s[j][kk] = W2[j * DD + k0 + kk];
        }
        __syncthreads();
        for (int c = 0; c < 4; ++c) {
            float4 w1a = *((const float4*)&W1s[jg][c * 4]);
            float4 w1b = *((const float4*)&W1s[jg + 64][c * 4]);
            float4 w2a = *((const float4*)&W2s[jg][c * 4]);
            float4 w2b = *((const float4*)&W2s[jg + 64][c * 4]);
            const int kk = k0 + c * 4;
            for (int n = 0; n < 8; ++n) {
                float4 h = *((const float4*)&Hs[n0 + n][kk]);
                float4 eh = *((const float4*)&EHs[n0 + n][kk]);
                acc1a[n] += h.x * w1a.x + h.y * w1a.y + h.z * w1a.z + h.w * w1a.w;
                acc1b[n] += h.x * w1b.x + h.y * w1b.y + h.z * w1b.z + h.w * w1b.w;
                acc2a[n] += eh.x * w2a.x + eh.y * w2a.y + eh.z * w2a.z + eh.w * w2a.w;
                acc2b[n] += eh.x * w2b.x + eh.y * w2b.y + eh.z * w2b.z + eh.w * w2b.w;
            }
        }
    }

    const float b1a = b1[jg], b1b = b1[jg + 64];
    const float b2a = b2[jg], b2b = b2[jg + 64];
    for (int n = 0; n < 8; ++n) {
        if (n0 + n < nvalid) {
            const int v = v0 + n0 + n;
            float x1 = acc1a[n] + b1a;
            x1 = x1 > 0.f ? x1 : SLOPE * x1;
            float x2 = acc2a[n] + b2a;
            x2 = x2 > 0.f ? x2 : SLOPE * x2;
            out[(size_t)v * DD + jg] = x1 + x2;
            float y1 = acc1b[n] + b1b;
            y1 = y1 > 0.f ? y1 : SLOPE * y1;
            float y2 = acc2b[n] + b2b;
            y2 = y2 > 0.f ? y2 : SLOPE * y2;
            out[(size_t)v * DD + jg + 64] = y1 + y2;
        }
    }
}

extern "C" void kernel_launch(void* const* d_in, const int* in_sizes, int n_in,
                              void* d_out, int out_size, void* d_ws, size_t ws_size,
                              hipStream_t stream)
{
    const float* E  = (const float*)d_in[0];
    const float* W1 = (const float*)d_in[1];
    const float* b1 = (const float*)d_in[2];
    const float* W2 = (const float*)d_in[3];
    const float* b2 = (const float*)d_in[4];
    const int* src  = (const int*)d_in[5];
    const int* dst  = (const int*)d_in[6];
    float* out = (float*)d_out;
    const int n_edges = in_sizes[5];

    char* ws = (char*)d_ws;
    const size_t hbytes = (size_t)NN * DD * sizeof(float);

    // ws layout: cnt[NN] | ovf_cnt | pad | ovf[OVCAP] | lists[NN*CAP] | (H)
    const size_t off_cnt   = 0;
    const size_t off_ovfc  = off_cnt + (size_t)NN * 4;
    const size_t off_ovf   = (off_ovfc + 4 + 255) & ~(size_t)255;
    const size_t off_lists = (off_ovf + (size_t)OVCAP * 8 + 255) & ~(size_t)255;
    const size_t off_H     = (off_lists + (size_t)NN * CAP * 4 + 255) & ~(size_t)255;
    const bool fast = ws_size >= off_H;                 // lists fit
    const bool h_in_ws = ws_size >= off_H + hbytes;

    // H may overlay d_out: gather fully overwrites it; fused_mlp stages its own
    // 32 rows to LDS before writing them.
    float* H = h_in_ws ? (float*)(ws + off_H)
                       : (ws_size >= hbytes && !fast ? (float*)ws : out);

    if (fast) {
        int*  cnt     = (int*)(ws + off_cnt);
        int*  ovf_cnt = (int*)(ws + off_ovfc);
        int2* ovf     = (int2*)(ws + off_ovf);
        int*  lists   = (int*)(ws + off_lists);
        if (!h_in_ws) H = out;

        hipMemsetAsync(ws + off_cnt, 0, (size_t)NN * 4 + 4 + 4, stream);
        place_edges<<<(n_edges + 255) / 256, 256, 0, stream>>>(
            src, dst, cnt, lists, ovf_cnt, ovf, n_edges);
        gather_sum<<<(NN * 32 + 255) / 256, 256, 0, stream>>>(E, cnt, lists, H);
        apply_overflow<<<32, 256, 0, stream>>>(ovf_cnt, ovf, E, H);
    } else {
        hipMemsetAsync(H, 0, hbytes, stream);
        scatter_add<<<((n_edges * 32) + 255) / 256, 256, 0, stream>>>(
            E, src, dst, H, n_edges);
    }

    fused_mlp<<<(NN + 31) / 32, 256, 0, stream>>>(E, H, W1, b1, W2, b2, out);
}

// Round 3
// 302.051 us; speedup vs baseline: 9.8452x; 1.7561x over previous
//
#include <hip/hip_runtime.h>

#define NN 50000
#define DD 128
#define SLOPE 0.01f
#define CAP 96        // max deg ~58 for Binomial(1.6M, 1/50k); 96 is >6 sigma past
#define OVCAP 8192

using bf16x8 = __attribute__((ext_vector_type(8))) short;
using f32x4  = __attribute__((ext_vector_type(4))) float;

// ---------------- bf16 helpers (RNE) ----------------
__device__ inline float bflo(unsigned int w) { return __uint_as_float(w << 16); }
__device__ inline float bfhi(unsigned int w) { return __uint_as_float(w & 0xffff0000u); }
__device__ inline unsigned int rnebf(float f) {
    unsigned int u = __float_as_uint(f);
    return (u + 0x7fffu + ((u >> 16) & 1u)) >> 16;
}
__device__ inline unsigned int pack2(float lo, float hi) {
    return rnebf(lo) | (rnebf(hi) << 16);
}
__device__ inline void unpack8(uint4 r, float* f) {
    f[0] = bflo(r.x); f[1] = bfhi(r.x); f[2] = bflo(r.y); f[3] = bfhi(r.y);
    f[4] = bflo(r.z); f[5] = bfhi(r.z); f[6] = bflo(r.w); f[7] = bfhi(r.w);
}
__device__ inline uint4 pack8(const float* f) {
    uint4 o;
    o.x = pack2(f[0], f[1]); o.y = pack2(f[2], f[3]);
    o.z = pack2(f[4], f[5]); o.w = pack2(f[6], f[7]);
    return o;
}
__device__ inline void addrow(float* acc, uint4 r) {
    acc[0] += bflo(r.x); acc[1] += bfhi(r.x);
    acc[2] += bflo(r.y); acc[3] += bfhi(r.y);
    acc[4] += bflo(r.z); acc[5] += bfhi(r.z);
    acc[6] += bflo(r.w); acc[7] += bfhi(r.w);
}

// ---------------------------------------------------------------------------
// Convert E (6.4M), W1, W2 (16K each) fp32 -> bf16. 8 floats / thread.
// ---------------------------------------------------------------------------
__global__ __launch_bounds__(256) void convert_bf(
    const float* __restrict__ E, const float* __restrict__ W1,
    const float* __restrict__ W2, unsigned short* __restrict__ Ebf,
    unsigned short* __restrict__ W1b, unsigned short* __restrict__ W2b)
{
    const int NE8 = NN * DD / 8;      // 800000
    const int NW8 = DD * DD / 8;      // 2048
    int t = blockIdx.x * 256 + threadIdx.x;
    const float* s; unsigned short* d; int idx;
    if (t < NE8)            { s = E;  d = Ebf; idx = t; }
    else if (t < NE8 + NW8) { s = W1; d = W1b; idx = t - NE8; }
    else if (t < NE8 + 2 * NW8) { s = W2; d = W2b; idx = t - NE8 - NW8; }
    else return;
    float4 a = ((const float4*)s)[(size_t)idx * 2];
    float4 b = ((const float4*)s)[(size_t)idx * 2 + 1];
    uint4 o;
    o.x = pack2(a.x, a.y); o.y = pack2(a.z, a.w);
    o.z = pack2(b.x, b.y); o.w = pack2(b.z, b.w);
    ((uint4*)d)[idx] = o;
}

// ---------------------------------------------------------------------------
// Build padded per-destination source lists (1.6M int atomics on L2 counters).
// ---------------------------------------------------------------------------
__global__ __launch_bounds__(256) void place_edges(
    const int* __restrict__ src, const int* __restrict__ dst,
    int* __restrict__ cnt, int* __restrict__ lists,
    int* __restrict__ ovf_cnt, int2* __restrict__ ovf, int n_edges)
{
    int e = blockIdx.x * 256 + threadIdx.x;
    if (e >= n_edges) return;
    int v = dst[e];
    int pos = atomicAdd(&cnt[v], 1);
    if (pos < CAP) {
        lists[v * CAP + pos] = src[e];
    } else {
        int oi = atomicAdd(ovf_cnt, 1);
        if (oi < OVCAP) ovf[oi] = make_int2(src[e], v);
    }
}

// ---------------------------------------------------------------------------
// H[v] = sum E_bf[u]; writes Hb and EHb = Ebf[v]*H as bf16. 16 lanes/node,
// 16B chunk each; fp32 accumulate. bf16 rows halve the L2/L3 gather traffic.
// ---------------------------------------------------------------------------
__global__ __launch_bounds__(256) void gather_bf(
    const unsigned short* __restrict__ Ebf, const int* __restrict__ cnt,
    const int* __restrict__ lists, unsigned short* __restrict__ Hb,
    unsigned short* __restrict__ EHb)
{
    int t = blockIdx.x * 256 + threadIdx.x;
    int v = t >> 4;
    if (v >= NN) return;
    int c = t & 15;
    int n = cnt[v]; n = n < CAP ? n : CAP;
    const int* lst = lists + v * CAP;
    const uint4* E4 = (const uint4*)Ebf;   // row = 16 x 16B chunks
    float acc[8] = {};
    int i = 0;
    for (; i + 4 <= n; i += 4) {           // 4 row-loads in flight
        int4 u4 = *(const int4*)(lst + i);
        uint4 r0 = E4[(size_t)u4.x * 16 + c];
        uint4 r1 = E4[(size_t)u4.y * 16 + c];
        uint4 r2 = E4[(size_t)u4.z * 16 + c];
        uint4 r3 = E4[(size_t)u4.w * 16 + c];
        addrow(acc, r0); addrow(acc, r1); addrow(acc, r2); addrow(acc, r3);
    }
    for (; i < n; ++i) addrow(acc, E4[(size_t)lst[i] * 16 + c]);

    float ef[8]; unpack8(E4[(size_t)v * 16 + c], ef);
    float eh[8];
    #pragma unroll
    for (int j = 0; j < 8; ++j) eh[j] = ef[j] * acc[j];
    ((uint4*)Hb)[(size_t)v * 16 + c] = pack8(acc);
    ((uint4*)EHb)[(size_t)v * 16 + c] = pack8(eh);
}

// Safety net for cnt>CAP (expected zero entries). Single wave, serial.
__global__ void fix_overflow_bf(
    const int* __restrict__ ovf_cnt, const int2* __restrict__ ovf,
    const unsigned short* __restrict__ Ebf, unsigned short* __restrict__ Hb,
    unsigned short* __restrict__ EHb)
{
    int total = *ovf_cnt; total = total < OVCAP ? total : OVCAP;
    if (total == 0) return;
    int c = threadIdx.x;
    if (c >= 16) return;
    for (int i = 0; i < total; ++i) {
        int u = ovf[i].x, v = ovf[i].y;
        float hf[8], ef[8], evf[8], eh[8];
        unpack8(((const uint4*)Hb)[(size_t)v * 16 + c], hf);
        unpack8(((const uint4*)Ebf)[(size_t)u * 16 + c], ef);
        #pragma unroll
        for (int j = 0; j < 8; ++j) hf[j] += ef[j];
        ((uint4*)Hb)[(size_t)v * 16 + c] = pack8(hf);
        unpack8(((const uint4*)Ebf)[(size_t)v * 16 + c], evf);
        #pragma unroll
        for (int j = 0; j < 8; ++j) eh[j] = evf[j] * hf[j];
        ((uint4*)EHb)[(size_t)v * 16 + c] = pack8(eh);
    }
}

// ---------------------------------------------------------------------------
// out = leaky(Hb @ W1b^T + b1) + leaky(EHb @ W2b^T + b2), 16x16x32 bf16 MFMA.
// LDS-free: wave owns 16 rows; A-frags (Hb/EHb) in regs across all 8 j-tiles;
// B-frags (W rows, 64KB total both mats) read from global -> L1/L2 hits.
// A layout: A[m=lane&15][k=quad*8+j]; C/D: col=lane&15, row=quad*4+reg (m89).
// ---------------------------------------------------------------------------
__global__ __launch_bounds__(256) void gemm_bf(
    const unsigned short* __restrict__ Hb, const unsigned short* __restrict__ EHb,
    const unsigned short* __restrict__ W1b, const unsigned short* __restrict__ W2b,
    const float* __restrict__ b1, const float* __restrict__ b2,
    float* __restrict__ out)
{
    const int wave = threadIdx.x >> 6;
    const int lane = threadIdx.x & 63;
    const int v0 = blockIdx.x * 64 + wave * 16;   // 50000 = 16*3125: tiles full
    if (v0 >= NN) return;
    const int m = lane & 15;
    const int quad = lane >> 4;

    bf16x8 aH[4], aE[4];
    const unsigned short* hrow = Hb  + (size_t)(v0 + m) * DD + quad * 8;
    const unsigned short* erow = EHb + (size_t)(v0 + m) * DD + quad * 8;
    #pragma unroll
    for (int ks = 0; ks < 4; ++ks) {
        aH[ks] = *(const bf16x8*)(hrow + ks * 32);
        aE[ks] = *(const bf16x8*)(erow + ks * 32);
    }

    #pragma unroll
    for (int jt = 0; jt < 8; ++jt) {
        const int j0 = jt * 16;
        const unsigned short* w1r = W1b + (size_t)(j0 + m) * DD + quad * 8;
        const unsigned short* w2r = W2b + (size_t)(j0 + m) * DD + quad * 8;
        f32x4 acc1 = {0.f, 0.f, 0.f, 0.f}, acc2 = {0.f, 0.f, 0.f, 0.f};
        #pragma unroll
        for (int ks = 0; ks < 4; ++ks) {
            bf16x8 bw1 = *(const bf16x8*)(w1r + ks * 32);
            bf16x8 bw2 = *(const bf16x8*)(w2r + ks * 32);
            acc1 = __builtin_amdgcn_mfma_f32_16x16x32_bf16(aH[ks], bw1, acc1, 0, 0, 0);
            acc2 = __builtin_amdgcn_mfma_f32_16x16x32_bf16(aE[ks], bw2, acc2, 0, 0, 0);
        }
        const float bb1 = b1[j0 + m], bb2 = b2[j0 + m];
        #pragma unroll
        for (int i = 0; i < 4; ++i) {
            float x1 = acc1[i] + bb1; x1 = x1 > 0.f ? x1 : SLOPE * x1;
            float x2 = acc2[i] + bb2; x2 = x2 > 0.f ? x2 : SLOPE * x2;
            out[(size_t)(v0 + quad * 4 + i) * DD + j0 + m] = x1 + x2;
        }
    }
}

// ======================= fallback fp32 path (round-2, proven) ==============
__global__ __launch_bounds__(256) void gather_sum(
    const float* __restrict__ E, const int* __restrict__ cnt,
    const int* __restrict__ lists, float* __restrict__ H)
{
    int t = blockIdx.x * 256 + threadIdx.x;
    int v = t >> 5;
    if (v >= NN) return;
    int c = t & 31;
    int n = cnt[v]; n = n < CAP ? n : CAP;
    const int* lst = lists + v * CAP;
    const float4* E4 = (const float4*)E;
    float4 acc = make_float4(0.f, 0.f, 0.f, 0.f);
    int i = 0;
    for (; i + 4 <= n; i += 4) {
        int4 u4 = *((const int4*)(lst + i));
        float4 a = E4[(size_t)u4.x * 32 + c];
        float4 b = E4[(size_t)u4.y * 32 + c];
        float4 d = E4[(size_t)u4.z * 32 + c];
        float4 f = E4[(size_t)u4.w * 32 + c];
        acc.x += a.x + b.x + d.x + f.x;
        acc.y += a.y + b.y + d.y + f.y;
        acc.z += a.z + b.z + d.z + f.z;
        acc.w += a.w + b.w + d.w + f.w;
    }
    for (; i < n; ++i) {
        float4 a = E4[(size_t)lst[i] * 32 + c];
        acc.x += a.x; acc.y += a.y; acc.z += a.z; acc.w += a.w;
    }
    ((float4*)H)[(size_t)v * 32 + c] = acc;
}

__global__ __launch_bounds__(256) void apply_overflow(
    const int* __restrict__ ovf_cnt, const int2* __restrict__ ovf,
    const float* __restrict__ E, float* __restrict__ H)
{
    int total = *ovf_cnt; total = total < OVCAP ? total : OVCAP;
    int work = total * 32;
    for (int t = blockIdx.x * 256 + threadIdx.x; t < work; t += gridDim.x * 256) {
        int i = t >> 5, c = t & 31;
        int2 edge = ovf[i];
        float4 a = ((const float4*)E)[(size_t)edge.x * 32 + c];
        float* hp = H + (size_t)edge.y * DD + c * 4;
        atomicAdd(hp + 0, a.x); atomicAdd(hp + 1, a.y);
        atomicAdd(hp + 2, a.z); atomicAdd(hp + 3, a.w);
    }
}

__global__ __launch_bounds__(256) void scatter_add(
    const float* __restrict__ E, const int* __restrict__ src,
    const int* __restrict__ dst, float* __restrict__ H, int n_edges)
{
    int t = blockIdx.x * 256 + threadIdx.x;
    int e = t >> 5;
    if (e >= n_edges) return;
    int c = t & 31;
    float4 a = ((const float4*)E)[(size_t)src[e] * 32 + c];
    float* hp = H + (size_t)dst[e] * DD + c * 4;
    atomicAdd(hp + 0, a.x); atomicAdd(hp + 1, a.y);
    atomicAdd(hp + 2, a.z); atomicAdd(hp + 3, a.w);
}

__global__ __launch_bounds__(256) void fused_mlp(
    const float* __restrict__ E, const float* __restrict__ H,
    const float* __restrict__ W1, const float* __restrict__ b1,
    const float* __restrict__ W2, const float* __restrict__ b2,
    float* __restrict__ out)
{
    __shared__ float Hs[32][DD];
    __shared__ float EHs[32][DD];
    __shared__ float W1s[DD][20];
    __shared__ float W2s[DD][20];
    const int tid = threadIdx.x;
    const int v0 = blockIdx.x * 32;
    const int nvalid = min(32, NN - v0);
    for (int i = 0; i < 4; ++i) {
        int f = tid + 256 * i;
        int n = f >> 5, c = f & 31;
        float4 h = make_float4(0.f, 0.f, 0.f, 0.f);
        float4 eh = h;
        if (n < nvalid) {
            h = ((const float4*)H)[(size_t)(v0 + n) * 32 + c];
            float4 e4 = ((const float4*)E)[(size_t)(v0 + n) * 32 + c];
            eh = make_float4(e4.x * h.x, e4.y * h.y, e4.z * h.z, e4.w * h.w);
        }
        *((float4*)&Hs[n][c * 4]) = h;
        *((float4*)&EHs[n][c * 4]) = eh;
    }
    const int jg = tid & 63;
    const int n0 = (tid >> 6) * 8;
    float acc1a[8] = {}, acc1b[8] = {}, acc2a[8] = {}, acc2b[8] = {};
    for (int t8 = 0; t8 < 8; ++t8) {
        const int k0 = t8 * 16;
        __syncthreads();
        for (int i = 0; i < 8; ++i) {
            int f = tid + 256 * i;
            int j = f >> 4, kk = f & 15;
            W1s[j][kk] = W1[j * DD + k0 + kk];
            W2s[j][kk] = W2[j * DD + k0 + kk];
        }
        __syncthreads();
        for (int c = 0; c < 4; ++c) {
            float4 w1a = *((const float4*)&W1s[jg][c * 4]);
            float4 w1b = *((const float4*)&W1s[jg + 64][c * 4]);
            float4 w2a = *((const float4*)&W2s[jg][c * 4]);
            float4 w2b = *((const float4*)&W2s[jg + 64][c * 4]);
            const int kk = k0 + c * 4;
            for (int n = 0; n < 8; ++n) {
                float4 h = *((const float4*)&Hs[n0 + n][kk]);
                float4 eh = *((const float4*)&EHs[n0 + n][kk]);
                acc1a[n] += h.x * w1a.x + h.y * w1a.y + h.z * w1a.z + h.w * w1a.w;
                acc1b[n] += h.x * w1b.x + h.y * w1b.y + h.z * w1b.z + h.w * w1b.w;
                acc2a[n] += eh.x * w2a.x + eh.y * w2a.y + eh.z * w2a.z + eh.w * w2a.w;
                acc2b[n] += eh.x * w2b.x + eh.y * w2b.y + eh.z * w2b.z + eh.w * w2b.w;
            }
        }
    }
    const float b1a = b1[jg], b1b = b1[jg + 64];
    const float b2a = b2[jg], b2b = b2[jg + 64];
    for (int n = 0; n < 8; ++n) {
        if (n0 + n < nvalid) {
            const int v = v0 + n0 + n;
            float x1 = acc1a[n] + b1a; x1 = x1 > 0.f ? x1 : SLOPE * x1;
            float x2 = acc2a[n] + b2a; x2 = x2 > 0.f ? x2 : SLOPE * x2;
            out[(size_t)v * DD + jg] = x1 + x2;
            float y1 = acc1b[n] + b1b; y1 = y1 > 0.f ? y1 : SLOPE * y1;
            float y2 = acc2b[n] + b2b; y2 = y2 > 0.f ? y2 : SLOPE * y2;
            out[(size_t)v * DD + jg + 64] = y1 + y2;
        }
    }
}
// ===========================================================================

extern "C" void kernel_launch(void* const* d_in, const int* in_sizes, int n_in,
                              void* d_out, int out_size, void* d_ws, size_t ws_size,
                              hipStream_t stream)
{
    const float* E  = (const float*)d_in[0];
    const float* W1 = (const float*)d_in[1];
    const float* b1 = (const float*)d_in[2];
    const float* W2 = (const float*)d_in[3];
    const float* b2 = (const float*)d_in[4];
    const int* src  = (const int*)d_in[5];
    const int* dst  = (const int*)d_in[6];
    float* out = (float*)d_out;
    const int n_edges = in_sizes[5];

    char* ws = (char*)d_ws;
    auto al = [](size_t x) { return (x + 255) & ~(size_t)255; };

    // bf16-path layout
    const size_t off_cnt   = 0;
    const size_t off_ovfc  = (size_t)NN * 4;
    const size_t off_ovf   = al(off_ovfc + 4);
    const size_t off_lists = al(off_ovf + (size_t)OVCAP * 8);
    const size_t off_Ebf   = al(off_lists + (size_t)NN * CAP * 4);
    const size_t off_Hb    = al(off_Ebf + (size_t)NN * DD * 2);
    const size_t off_EHb   = al(off_Hb + (size_t)NN * DD * 2);
    const size_t off_W1b   = al(off_EHb + (size_t)NN * DD * 2);
    const size_t off_W2b   = al(off_W1b + (size_t)DD * DD * 2);
    const size_t need_bf   = off_W2b + (size_t)DD * DD * 2;   // ~58 MB

    if (ws_size >= need_bf) {
        int* cnt      = (int*)(ws + off_cnt);
        int* ovf_cnt  = (int*)(ws + off_ovfc);
        int2* ovf     = (int2*)(ws + off_ovf);
        int* lists    = (int*)(ws + off_lists);
        unsigned short* Ebf = (unsigned short*)(ws + off_Ebf);
        unsigned short* Hb  = (unsigned short*)(ws + off_Hb);
        unsigned short* EHb = (unsigned short*)(ws + off_EHb);
        unsigned short* W1b = (unsigned short*)(ws + off_W1b);
        unsigned short* W2b = (unsigned short*)(ws + off_W2b);

        hipMemsetAsync(ws, 0, off_ovf, stream);   // cnt + ovf_cnt
        const int ncv = NN * DD / 8 + 2 * (DD * DD / 8);
        convert_bf<<<(ncv + 255) / 256, 256, 0, stream>>>(E, W1, W2, Ebf, W1b, W2b);
        place_edges<<<(n_edges + 255) / 256, 256, 0, stream>>>(
            src, dst, cnt, lists, ovf_cnt, ovf, n_edges);
        gather_bf<<<(NN * 16 + 255) / 256, 256, 0, stream>>>(Ebf, cnt, lists, Hb, EHb);
        fix_overflow_bf<<<1, 64, 0, stream>>>(ovf_cnt, ovf, Ebf, Hb, EHb);
        gemm_bf<<<(NN + 63) / 64, 256, 0, stream>>>(Hb, EHb, W1b, W2b, b1, b2, out);
        return;
    }

    // ---------------- fallback: round-2 fp32 path ----------------
    const size_t hbytes = (size_t)NN * DD * sizeof(float);
    const size_t off_H = al(off_lists + (size_t)NN * CAP * 4);
    const bool fast = ws_size >= off_H;
    const bool h_in_ws = ws_size >= off_H + hbytes;
    float* H = h_in_ws ? (float*)(ws + off_H)
                       : (ws_size >= hbytes && !fast ? (float*)ws : out);
    if (fast) {
        int* cnt     = (int*)(ws + off_cnt);
        int* ovf_cnt = (int*)(ws + off_ovfc);
        int2* ovf    = (int2*)(ws + off_ovf);
        int* lists   = (int*)(ws + off_lists);
        if (!h_in_ws) H = out;
        hipMemsetAsync(ws, 0, off_ovf, stream);
        place_edges<<<(n_edges + 255) / 256, 256, 0, stream>>>(
            src, dst, cnt, lists, ovf_cnt, ovf, n_edges);
        gather_sum<<<(NN * 32 + 255) / 256, 256, 0, stream>>>(E, cnt, lists, H);
        apply_overflow<<<32, 256, 0, stream>>>(ovf_cnt, ovf, E, H);
    } else {
        hipMemsetAsync(H, 0, hbytes, stream);
        scatter_add<<<((n_edges * 32) + 255) / 256, 256, 0, stream>>>(
            E, src, dst, H, n_edges);
    }
    fused_mlp<<<(NN + 31) / 32, 256, 0, stream>>>(E, H, W1, b1, W2, b2, out);
}

// Round 4
// 284.119 us; speedup vs baseline: 10.4666x; 1.0631x over previous
//
#include <hip/hip_runtime.h>

#define NN 50000
#define DD 128
#define SLOPE 0.01f
#define NB 782        // buckets of 64 nodes: bucket = v>>6, v<50000 -> 0..781
#define SCAP 512      // per (shard,bucket) staging cap; mean 256, sigma 16
#define OVCAP 8192

using bf16x8 = __attribute__((ext_vector_type(8))) short;
using f32x4  = __attribute__((ext_vector_type(4))) float;

// ---------------- bf16 helpers (RNE) ----------------
__device__ inline float bflo(unsigned int w) { return __uint_as_float(w << 16); }
__device__ inline float bfhi(unsigned int w) { return __uint_as_float(w & 0xffff0000u); }
__device__ inline unsigned int rnebf(float f) {
    unsigned int u = __float_as_uint(f);
    return (u + 0x7fffu + ((u >> 16) & 1u)) >> 16;
}
__device__ inline unsigned int pack2(float lo, float hi) {
    return rnebf(lo) | (rnebf(hi) << 16);
}
__device__ inline void unpack8(uint4 r, float* f) {
    f[0] = bflo(r.x); f[1] = bfhi(r.x); f[2] = bflo(r.y); f[3] = bfhi(r.y);
    f[4] = bflo(r.z); f[5] = bfhi(r.z); f[6] = bflo(r.w); f[7] = bfhi(r.w);
}
__device__ inline uint4 pack8(const float* f) {
    uint4 o;
    o.x = pack2(f[0], f[1]); o.y = pack2(f[2], f[3]);
    o.z = pack2(f[4], f[5]); o.w = pack2(f[6], f[7]);
    return o;
}
__device__ inline void addrow(float* acc, uint4 r) {
    acc[0] += bflo(r.x); acc[1] += bfhi(r.x);
    acc[2] += bflo(r.y); acc[3] += bfhi(r.y);
    acc[4] += bflo(r.z); acc[5] += bfhi(r.z);
    acc[6] += bflo(r.w); acc[7] += bfhi(r.w);
}

// ---------------------------------------------------------------------------
// fp32 -> bf16 conversion of E, W1, W2.
// ---------------------------------------------------------------------------
__global__ __launch_bounds__(256) void convert_bf(
    const float* __restrict__ E, const float* __restrict__ W1,
    const float* __restrict__ W2, unsigned short* __restrict__ Ebf,
    unsigned short* __restrict__ W1b, unsigned short* __restrict__ W2b)
{
    const int NE8 = NN * DD / 8;
    const int NW8 = DD * DD / 8;
    int t = blockIdx.x * 256 + threadIdx.x;
    const float* s; unsigned short* d; int idx;
    if (t < NE8)                { s = E;  d = Ebf; idx = t; }
    else if (t < NE8 + NW8)     { s = W1; d = W1b; idx = t - NE8; }
    else if (t < NE8 + 2 * NW8) { s = W2; d = W2b; idx = t - NE8 - NW8; }
    else return;
    float4 a = ((const float4*)s)[(size_t)idx * 2];
    float4 b = ((const float4*)s)[(size_t)idx * 2 + 1];
    uint4 o;
    o.x = pack2(a.x, a.y); o.y = pack2(a.z, a.w);
    o.z = pack2(b.x, b.y); o.w = pack2(b.z, b.w);
    ((uint4*)d)[idx] = o;
}

// ---------------------------------------------------------------------------
// Bin edges into (shard, bucket) staging segments. shard = blockIdx & 7
// (XCD proxy under round-robin dispatch) keeps each tail's 64B lines written
// by one XCD and filled by 16 consecutive appends -> full-line evictions.
// Record: src (16b) | (v & 63) << 16.
// ---------------------------------------------------------------------------
__global__ __launch_bounds__(256) void bin_edges(
    const int* __restrict__ src, const int* __restrict__ dst,
    int* __restrict__ tail, unsigned int* __restrict__ stag,
    int* __restrict__ ovf_cnt, int2* __restrict__ ovf, int n_edges)
{
    int e = blockIdx.x * 256 + threadIdx.x;
    if (e >= n_edges) return;
    int v = dst[e];
    int u = src[e];
    int cell = (blockIdx.x & 7) * NB + (v >> 6);
    int pos = atomicAdd(&tail[cell], 1);
    if (pos < SCAP) {
        stag[(size_t)cell * SCAP + pos] =
            (unsigned int)u | ((unsigned int)(v & 63) << 16);
    } else {
        int oi = atomicAdd(ovf_cnt, 1);
        if (oi < OVCAP) ovf[oi] = make_int2(u, v);
    }
}

// ---------------------------------------------------------------------------
// One block per bucket (64 nodes). Counting-sort the bucket's records in LDS
// (counts -> prefix -> place), then gather-sum E rows per node from the
// LDS-resident sorted lists; write Hb and EHb = Ebf[v]*H directly.
// ---------------------------------------------------------------------------
__global__ __launch_bounds__(256) void bucket_gather(
    const unsigned short* __restrict__ Ebf, const int* __restrict__ tail,
    const unsigned int* __restrict__ stag, unsigned short* __restrict__ Hb,
    unsigned short* __restrict__ EHb)
{
    __shared__ unsigned short sorted[8 * SCAP];  // 8 KB, max possible
    __shared__ int cnt[64], off[65], pos[64];

    const int b = blockIdx.x;
    const int tid = threadIdx.x;

    if (tid < 64) cnt[tid] = 0;
    __syncthreads();

    // pass 1: count per node-low
    for (int s = 0; s < 8; ++s) {
        int len = tail[s * NB + b]; len = len < SCAP ? len : SCAP;
        const unsigned int* seg = stag + (size_t)(s * NB + b) * SCAP;
        for (int i = tid; i < len; i += 256)
            atomicAdd(&cnt[(seg[i] >> 16) & 63], 1);
    }
    __syncthreads();
    if (tid == 0) {
        int a = 0;
        for (int j = 0; j < 64; ++j) { off[j] = a; pos[j] = a; a += cnt[j]; }
        off[64] = a;
    }
    __syncthreads();
    // pass 2: place src ids into sorted order
    for (int s = 0; s < 8; ++s) {
        int len = tail[s * NB + b]; len = len < SCAP ? len : SCAP;
        const unsigned int* seg = stag + (size_t)(s * NB + b) * SCAP;
        for (int i = tid; i < len; i += 256) {
            unsigned int r = seg[i];
            int p = atomicAdd(&pos[(r >> 16) & 63], 1);
            sorted[p] = (unsigned short)(r & 0xffffu);
        }
    }
    __syncthreads();

    // gather: 16 lanes per node x 16 nodes per pass, 4 passes
    const int g = tid >> 4;      // node slot within pass
    const int c = tid & 15;      // 16B chunk within row
    const uint4* E4 = (const uint4*)Ebf;
    for (int p4 = 0; p4 < 4; ++p4) {
        int nl = p4 * 16 + g;
        int v = b * 64 + nl;
        if (v >= NN) continue;
        float acc[8] = {};
        int i = off[nl], e1 = off[nl + 1];
        for (; i + 2 <= e1; i += 2) {
            uint4 r0 = E4[(size_t)sorted[i] * 16 + c];
            uint4 r1 = E4[(size_t)sorted[i + 1] * 16 + c];
            addrow(acc, r0); addrow(acc, r1);
        }
        if (i < e1) addrow(acc, E4[(size_t)sorted[i] * 16 + c]);

        float ef[8]; unpack8(E4[(size_t)v * 16 + c], ef);
        float eh[8];
        #pragma unroll
        for (int j = 0; j < 8; ++j) eh[j] = ef[j] * acc[j];
        ((uint4*)Hb)[(size_t)v * 16 + c] = pack8(acc);
        ((uint4*)EHb)[(size_t)v * 16 + c] = pack8(eh);
    }
}

// Safety net for staging overflow (expected empty). Single wave, serial.
__global__ void fix_overflow_bf(
    const int* __restrict__ ovf_cnt, const int2* __restrict__ ovf,
    const unsigned short* __restrict__ Ebf, unsigned short* __restrict__ Hb,
    unsigned short* __restrict__ EHb)
{
    int total = *ovf_cnt; total = total < OVCAP ? total : OVCAP;
    if (total == 0) return;
    int c = threadIdx.x;
    if (c >= 16) return;
    for (int i = 0; i < total; ++i) {
        int u = ovf[i].x, v = ovf[i].y;
        float hf[8], ef[8], evf[8], eh[8];
        unpack8(((const uint4*)Hb)[(size_t)v * 16 + c], hf);
        unpack8(((const uint4*)Ebf)[(size_t)u * 16 + c], ef);
        #pragma unroll
        for (int j = 0; j < 8; ++j) hf[j] += ef[j];
        ((uint4*)Hb)[(size_t)v * 16 + c] = pack8(hf);
        unpack8(((const uint4*)Ebf)[(size_t)v * 16 + c], evf);
        #pragma unroll
        for (int j = 0; j < 8; ++j) eh[j] = evf[j] * hf[j];
        ((uint4*)EHb)[(size_t)v * 16 + c] = pack8(eh);
    }
}

// ---------------------------------------------------------------------------
// out = leaky(Hb @ W1b^T + b1) + leaky(EHb @ W2b^T + b2), 16x16x32 bf16 MFMA.
// LDS-free; W rows from global (L1/L2-hit broadcasts).
// ---------------------------------------------------------------------------
__global__ __launch_bounds__(256) void gemm_bf(
    const unsigned short* __restrict__ Hb, const unsigned short* __restrict__ EHb,
    const unsigned short* __restrict__ W1b, const unsigned short* __restrict__ W2b,
    const float* __restrict__ b1, const float* __restrict__ b2,
    float* __restrict__ out)
{
    const int wave = threadIdx.x >> 6;
    const int lane = threadIdx.x & 63;
    const int v0 = blockIdx.x * 64 + wave * 16;
    if (v0 >= NN) return;
    const int m = lane & 15;
    const int quad = lane >> 4;

    bf16x8 aH[4], aE[4];
    const unsigned short* hrow = Hb  + (size_t)(v0 + m) * DD + quad * 8;
    const unsigned short* erow = EHb + (size_t)(v0 + m) * DD + quad * 8;
    #pragma unroll
    for (int ks = 0; ks < 4; ++ks) {
        aH[ks] = *(const bf16x8*)(hrow + ks * 32);
        aE[ks] = *(const bf16x8*)(erow + ks * 32);
    }

    #pragma unroll
    for (int jt = 0; jt < 8; ++jt) {
        const int j0 = jt * 16;
        const unsigned short* w1r = W1b + (size_t)(j0 + m) * DD + quad * 8;
        const unsigned short* w2r = W2b + (size_t)(j0 + m) * DD + quad * 8;
        f32x4 acc1 = {0.f, 0.f, 0.f, 0.f}, acc2 = {0.f, 0.f, 0.f, 0.f};
        #pragma unroll
        for (int ks = 0; ks < 4; ++ks) {
            bf16x8 bw1 = *(const bf16x8*)(w1r + ks * 32);
            bf16x8 bw2 = *(const bf16x8*)(w2r + ks * 32);
            acc1 = __builtin_amdgcn_mfma_f32_16x16x32_bf16(aH[ks], bw1, acc1, 0, 0, 0);
            acc2 = __builtin_amdgcn_mfma_f32_16x16x32_bf16(aE[ks], bw2, acc2, 0, 0, 0);
        }
        const float bb1 = b1[j0 + m], bb2 = b2[j0 + m];
        #pragma unroll
        for (int i = 0; i < 4; ++i) {
            float x1 = acc1[i] + bb1; x1 = x1 > 0.f ? x1 : SLOPE * x1;
            float x2 = acc2[i] + bb2; x2 = x2 > 0.f ? x2 : SLOPE * x2;
            out[(size_t)(v0 + quad * 4 + i) * DD + j0 + m] = x1 + x2;
        }
    }
}

// ============== minimal fallback (ws too small): fp32 atomics ==============
__global__ __launch_bounds__(256) void scatter_add(
    const float* __restrict__ E, const int* __restrict__ src,
    const int* __restrict__ dst, float* __restrict__ H, int n_edges)
{
    int t = blockIdx.x * 256 + threadIdx.x;
    int e = t >> 5;
    if (e >= n_edges) return;
    int c = t & 31;
    float4 a = ((const float4*)E)[(size_t)src[e] * 32 + c];
    float* hp = H + (size_t)dst[e] * DD + c * 4;
    atomicAdd(hp + 0, a.x); atomicAdd(hp + 1, a.y);
    atomicAdd(hp + 2, a.z); atomicAdd(hp + 3, a.w);
}

__global__ __launch_bounds__(256) void fused_mlp(
    const float* __restrict__ E, const float* __restrict__ H,
    const float* __restrict__ W1, const float* __restrict__ b1,
    const float* __restrict__ W2, const float* __restrict__ b2,
    float* __restrict__ out)
{
    __shared__ float Hs[32][DD];
    __shared__ float EHs[32][DD];
    __shared__ float W1s[DD][20];
    __shared__ float W2s[DD][20];
    const int tid = threadIdx.x;
    const int v0 = blockIdx.x * 32;
    const int nvalid = min(32, NN - v0);
    for (int i = 0; i < 4; ++i) {
        int f = tid + 256 * i;
        int n = f >> 5, c = f & 31;
        float4 h = make_float4(0.f, 0.f, 0.f, 0.f);
        float4 eh = h;
        if (n < nvalid) {
            h = ((const float4*)H)[(size_t)(v0 + n) * 32 + c];
            float4 e4 = ((const float4*)E)[(size_t)(v0 + n) * 32 + c];
            eh = make_float4(e4.x * h.x, e4.y * h.y, e4.z * h.z, e4.w * h.w);
        }
        *((float4*)&Hs[n][c * 4]) = h;
        *((float4*)&EHs[n][c * 4]) = eh;
    }
    const int jg = tid & 63;
    const int n0 = (tid >> 6) * 8;
    float acc1a[8] = {}, acc1b[8] = {}, acc2a[8] = {}, acc2b[8] = {};
    for (int t8 = 0; t8 < 8; ++t8) {
        const int k0 = t8 * 16;
        __syncthreads();
        for (int i = 0; i < 8; ++i) {
            int f = tid + 256 * i;
            int j = f >> 4, kk = f & 15;
            W1s[j][kk] = W1[j * DD + k0 + kk];
            W2s[j][kk] = W2[j * DD + k0 + kk];
        }
        __syncthreads();
        for (int c = 0; c < 4; ++c) {
            float4 w1a = *((const float4*)&W1s[jg][c * 4]);
            float4 w1b = *((const float4*)&W1s[jg + 64][c * 4]);
            float4 w2a = *((const float4*)&W2s[jg][c * 4]);
            float4 w2b = *((const float4*)&W2s[jg + 64][c * 4]);
            const int kk = k0 + c * 4;
            for (int n = 0; n < 8; ++n) {
                float4 h = *((const float4*)&Hs[n0 + n][kk]);
                float4 eh = *((const float4*)&EHs[n0 + n][kk]);
                acc1a[n] += h.x * w1a.x + h.y * w1a.y + h.z * w1a.z + h.w * w1a.w;
                acc1b[n] += h.x * w1b.x + h.y * w1b.y + h.z * w1b.z + h.w * w1b.w;
                acc2a[n] += eh.x * w2a.x + eh.y * w2a.y + eh.z * w2a.z + eh.w * w2a.w;
                acc2b[n] += eh.x * w2b.x + eh.y * w2b.y + eh.z * w2b.z + eh.w * w2b.w;
            }
        }
    }
    const float b1a = b1[jg], b1b = b1[jg + 64];
    const float b2a = b2[jg], b2b = b2[jg + 64];
    for (int n = 0; n < 8; ++n) {
        if (n0 + n < nvalid) {
            const int v = v0 + n0 + n;
            float x1 = acc1a[n] + b1a; x1 = x1 > 0.f ? x1 : SLOPE * x1;
            float x2 = acc2a[n] + b2a; x2 = x2 > 0.f ? x2 : SLOPE * x2;
            out[(size_t)v * DD + jg] = x1 + x2;
            float y1 = acc1b[n] + b1b; y1 = y1 > 0.f ? y1 : SLOPE * y1;
            float y2 = acc2b[n] + b2b; y2 = y2 > 0.f ? y2 : SLOPE * y2;
            out[(size_t)v * DD + jg + 64] = y1 + y2;
        }
    }
}
// ===========================================================================

extern "C" void kernel_launch(void* const* d_in, const int* in_sizes, int n_in,
                              void* d_out, int out_size, void* d_ws, size_t ws_size,
                              hipStream_t stream)
{
    const float* E  = (const float*)d_in[0];
    const float* W1 = (const float*)d_in[1];
    const float* b1 = (const float*)d_in[2];
    const float* W2 = (const float*)d_in[3];
    const float* b2 = (const float*)d_in[4];
    const int* src  = (const int*)d_in[5];
    const int* dst  = (const int*)d_in[6];
    float* out = (float*)d_out;
    const int n_edges = in_sizes[5];

    char* ws = (char*)d_ws;
    auto al = [](size_t x) { return (x + 255) & ~(size_t)255; };

    const size_t off_tail = 0;                                  // 8*NB*4
    const size_t off_ovfc = (size_t)8 * NB * 4;
    const size_t off_ovf  = al(off_ovfc + 4);
    const size_t off_stag = al(off_ovf + (size_t)OVCAP * 8);
    const size_t off_Ebf  = al(off_stag + (size_t)8 * NB * SCAP * 4);
    const size_t off_Hb   = al(off_Ebf + (size_t)NN * DD * 2);
    const size_t off_EHb  = al(off_Hb + (size_t)NN * DD * 2);
    const size_t off_W1b  = al(off_EHb + (size_t)NN * DD * 2);
    const size_t off_W2b  = al(off_W1b + (size_t)DD * DD * 2);
    const size_t need_bf  = off_W2b + (size_t)DD * DD * 2;      // ~51.5 MB

    if (ws_size >= need_bf) {
        int*  tailp   = (int*)(ws + off_tail);
        int*  ovf_cnt = (int*)(ws + off_ovfc);
        int2* ovf     = (int2*)(ws + off_ovf);
        unsigned int*   stag = (unsigned int*)(ws + off_stag);
        unsigned short* Ebf  = (unsigned short*)(ws + off_Ebf);
        unsigned short* Hb   = (unsigned short*)(ws + off_Hb);
        unsigned short* EHb  = (unsigned short*)(ws + off_EHb);
        unsigned short* W1b  = (unsigned short*)(ws + off_W1b);
        unsigned short* W2b  = (unsigned short*)(ws + off_W2b);

        hipMemsetAsync(ws, 0, off_ovf, stream);   // tails + ovf_cnt
        const int ncv = NN * DD / 8 + 2 * (DD * DD / 8);
        convert_bf<<<(ncv + 255) / 256, 256, 0, stream>>>(E, W1, W2, Ebf, W1b, W2b);
        bin_edges<<<(n_edges + 255) / 256, 256, 0, stream>>>(
            src, dst, tailp, stag, ovf_cnt, ovf, n_edges);
        bucket_gather<<<NB, 256, 0, stream>>>(Ebf, tailp, stag, Hb, EHb);
        fix_overflow_bf<<<1, 64, 0, stream>>>(ovf_cnt, ovf, Ebf, Hb, EHb);
        gemm_bf<<<(NN + 63) / 64, 256, 0, stream>>>(Hb, EHb, W1b, W2b, b1, b2, out);
        return;
    }

    // fallback: fp32 atomics into H (= ws if it fits, else out), then fused MLP
    const size_t hbytes = (size_t)NN * DD * sizeof(float);
    float* H = (ws_size >= hbytes) ? (float*)ws : out;
    hipMemsetAsync(H, 0, hbytes, stream);
    scatter_add<<<((n_edges * 32) + 255) / 256, 256, 0, stream>>>(
        E, src, dst, H, n_edges);
    fused_mlp<<<(NN + 31) / 32, 256, 0, stream>>>(E, H, W1, b1, W2, b2, out);
}

// Round 5
// 218.525 us; speedup vs baseline: 13.6083x; 1.3002x over previous
//
#include <hip/hip_runtime.h>

#define NN 50000
#define DD 128
#define SLOPE 0.01f
#define NB 782        // buckets of 64 nodes: bucket = v>>6
#define BCAP 2560     // per-bucket global cap; mean 2046, sigma 45 -> +11 sigma
#define ECH 8192      // edges per bin_sort block
#define OVCAP 8192

using bf16x8 = __attribute__((ext_vector_type(8))) short;
using f32x4  = __attribute__((ext_vector_type(4))) float;

// ---------------- bf16 helpers (RNE) ----------------
__device__ inline float bflo(unsigned int w) { return __uint_as_float(w << 16); }
__device__ inline float bfhi(unsigned int w) { return __uint_as_float(w & 0xffff0000u); }
__device__ inline unsigned int rnebf(float f) {
    unsigned int u = __float_as_uint(f);
    return (u + 0x7fffu + ((u >> 16) & 1u)) >> 16;
}
__device__ inline unsigned int pack2(float lo, float hi) {
    return rnebf(lo) | (rnebf(hi) << 16);
}
__device__ inline void unpack8(uint4 r, float* f) {
    f[0] = bflo(r.x); f[1] = bfhi(r.x); f[2] = bflo(r.y); f[3] = bfhi(r.y);
    f[4] = bflo(r.z); f[5] = bfhi(r.z); f[6] = bflo(r.w); f[7] = bfhi(r.w);
}
__device__ inline uint4 pack8(const float* f) {
    uint4 o;
    o.x = pack2(f[0], f[1]); o.y = pack2(f[2], f[3]);
    o.z = pack2(f[4], f[5]); o.w = pack2(f[6], f[7]);
    return o;
}
__device__ inline void addrow(float* acc, uint4 r) {
    acc[0] += bflo(r.x); acc[1] += bfhi(r.x);
    acc[2] += bflo(r.y); acc[3] += bfhi(r.y);
    acc[4] += bflo(r.z); acc[5] += bfhi(r.z);
    acc[6] += bflo(r.w); acc[7] += bfhi(r.w);
}

// ---------------------------------------------------------------------------
// fp32 -> bf16 conversion of E, W1, W2.
// ---------------------------------------------------------------------------
__global__ __launch_bounds__(256) void convert_bf(
    const float* __restrict__ E, const float* __restrict__ W1,
    const float* __restrict__ W2, unsigned short* __restrict__ Ebf,
    unsigned short* __restrict__ W1b, unsigned short* __restrict__ W2b)
{
    const int NE8 = NN * DD / 8;
    const int NW8 = DD * DD / 8;
    int t = blockIdx.x * 256 + threadIdx.x;
    const float* s; unsigned short* d; int idx;
    if (t < NE8)                { s = E;  d = Ebf; idx = t; }
    else if (t < NE8 + NW8)     { s = W1; d = W1b; idx = t - NE8; }
    else if (t < NE8 + 2 * NW8) { s = W2; d = W2b; idx = t - NE8 - NW8; }
    else return;
    float4 a = ((const float4*)s)[(size_t)idx * 2];
    float4 b = ((const float4*)s)[(size_t)idx * 2 + 1];
    uint4 o;
    o.x = pack2(a.x, a.y); o.y = pack2(a.z, a.w);
    o.z = pack2(b.x, b.y); o.w = pack2(b.z, b.w);
    ((uint4*)d)[idx] = o;
}

// ---------------------------------------------------------------------------
// Block-local LDS counting sort of 8192 edges by bucket (v>>6), then flush
// each bucket's run with ONE global atomicAdd + contiguous stores.
// Record: src (16b) | (v & 63) << 16.
// ---------------------------------------------------------------------------
__global__ __launch_bounds__(256) void bin_sort(
    const int* __restrict__ src, const int* __restrict__ dst,
    int* __restrict__ gtail, unsigned int* __restrict__ stag,
    int* __restrict__ ovf_cnt, int2* __restrict__ ovf, int n_edges)
{
    __shared__ unsigned int srt[ECH];     // 32 KB
    __shared__ int cnt[NB], off[NB], pos[NB];
    __shared__ int wsum[4];

    const int tid = threadIdx.x;
    const int e0 = blockIdx.x * ECH;
    const int m = min(ECH, n_edges - e0);

    for (int b = tid; b < NB; b += 256) cnt[b] = 0;
    __syncthreads();

    // pass 1: histogram (LDS atomics)
    for (int i = tid; i < m; i += 256)
        atomicAdd(&cnt[dst[e0 + i] >> 6], 1);
    __syncthreads();

    // exclusive prefix sum over NB: thread t covers buckets [4t, 4t+4)
    const int lane = tid & 63, w = tid >> 6;
    int b0 = tid * 4;
    int loc[4]; int s = 0;
    #pragma unroll
    for (int j = 0; j < 4; ++j) {
        int bb = b0 + j;
        int cv = (bb < NB) ? cnt[bb] : 0;
        loc[j] = s; s += cv;
    }
    int incl = s;
    #pragma unroll
    for (int d = 1; d < 64; d <<= 1) {
        int t2 = __shfl_up(incl, d);
        if (lane >= d) incl += t2;
    }
    if (lane == 63) wsum[w] = incl;
    __syncthreads();
    int wbase = 0;
    for (int w2 = 0; w2 < w; ++w2) wbase += wsum[w2];
    int base = wbase + incl - s;
    #pragma unroll
    for (int j = 0; j < 4; ++j) {
        int bb = b0 + j;
        if (bb < NB) { off[bb] = base + loc[j]; pos[bb] = base + loc[j]; }
    }
    __syncthreads();

    // pass 2: place records into LDS-sorted order
    for (int i = tid; i < m; i += 256) {
        int v = dst[e0 + i];
        int u = src[e0 + i];
        int p = atomicAdd(&pos[v >> 6], 1);
        srt[p] = (unsigned int)u | ((unsigned int)(v & 63) << 16);
    }
    __syncthreads();

    // flush: one global atomic per nonempty bucket, contiguous run copy
    for (int bb = tid; bb < NB; bb += 256) {
        int c = cnt[bb];
        if (!c) continue;
        int g = atomicAdd(&gtail[bb], c);
        int s0 = off[bb];
        unsigned int* dstp = stag + (size_t)bb * BCAP;
        for (int k = 0; k < c; ++k) {
            int gp = g + k;
            unsigned int r = srt[s0 + k];
            if (gp < BCAP) {
                dstp[gp] = r;
            } else {
                int oi = atomicAdd(ovf_cnt, 1);
                if (oi < OVCAP)
                    ovf[oi] = make_int2((int)(r & 0xffffu),
                                        bb * 64 + (int)((r >> 16) & 63));
            }
        }
    }
}

// ---------------------------------------------------------------------------
// One block per bucket (64 nodes). Counting-sort the bucket's records by
// node-low6 in LDS, then gather-sum E rows per node; write Hb, EHb.
// ---------------------------------------------------------------------------
__global__ __launch_bounds__(256) void bucket_gather(
    const unsigned short* __restrict__ Ebf, const int* __restrict__ gtail,
    const unsigned int* __restrict__ stag, unsigned short* __restrict__ Hb,
    unsigned short* __restrict__ EHb)
{
    __shared__ unsigned short sorted[BCAP];   // 5 KB
    __shared__ int cnt[64], off[65], pos[64];

    const int b = blockIdx.x;
    const int tid = threadIdx.x;
    int len = gtail[b]; len = len < BCAP ? len : BCAP;
    const unsigned int* seg = stag + (size_t)b * BCAP;

    if (tid < 64) cnt[tid] = 0;
    __syncthreads();
    for (int i = tid; i < len; i += 256)
        atomicAdd(&cnt[(seg[i] >> 16) & 63], 1);
    __syncthreads();
    if (tid == 0) {
        int a = 0;
        for (int j = 0; j < 64; ++j) { off[j] = a; pos[j] = a; a += cnt[j]; }
        off[64] = a;
    }
    __syncthreads();
    for (int i = tid; i < len; i += 256) {
        unsigned int r = seg[i];
        int p = atomicAdd(&pos[(r >> 16) & 63], 1);
        sorted[p] = (unsigned short)(r & 0xffffu);
    }
    __syncthreads();

    // gather: 16 lanes per node x 16 nodes per pass, 4 passes
    const int g = tid >> 4;
    const int c = tid & 15;
    const uint4* E4 = (const uint4*)Ebf;
    for (int p4 = 0; p4 < 4; ++p4) {
        int nl = p4 * 16 + g;
        int v = b * 64 + nl;
        if (v >= NN) continue;
        float acc[8] = {};
        int i = off[nl], e1 = off[nl + 1];
        for (; i + 4 <= e1; i += 4) {       // 4 row-loads in flight
            uint4 r0 = E4[(size_t)sorted[i]     * 16 + c];
            uint4 r1 = E4[(size_t)sorted[i + 1] * 16 + c];
            uint4 r2 = E4[(size_t)sorted[i + 2] * 16 + c];
            uint4 r3 = E4[(size_t)sorted[i + 3] * 16 + c];
            addrow(acc, r0); addrow(acc, r1); addrow(acc, r2); addrow(acc, r3);
        }
        for (; i < e1; ++i) addrow(acc, E4[(size_t)sorted[i] * 16 + c]);

        float ef[8]; unpack8(E4[(size_t)v * 16 + c], ef);
        float eh[8];
        #pragma unroll
        for (int j = 0; j < 8; ++j) eh[j] = ef[j] * acc[j];
        ((uint4*)Hb)[(size_t)v * 16 + c] = pack8(acc);
        ((uint4*)EHb)[(size_t)v * 16 + c] = pack8(eh);
    }
}

// Safety net for staging overflow (expected empty). Single wave, serial.
__global__ void fix_overflow_bf(
    const int* __restrict__ ovf_cnt, const int2* __restrict__ ovf,
    const unsigned short* __restrict__ Ebf, unsigned short* __restrict__ Hb,
    unsigned short* __restrict__ EHb)
{
    int total = *ovf_cnt; total = total < OVCAP ? total : OVCAP;
    if (total == 0) return;
    int c = threadIdx.x;
    if (c >= 16) return;
    for (int i = 0; i < total; ++i) {
        int u = ovf[i].x, v = ovf[i].y;
        float hf[8], ef[8], evf[8], eh[8];
        unpack8(((const uint4*)Hb)[(size_t)v * 16 + c], hf);
        unpack8(((const uint4*)Ebf)[(size_t)u * 16 + c], ef);
        #pragma unroll
        for (int j = 0; j < 8; ++j) hf[j] += ef[j];
        ((uint4*)Hb)[(size_t)v * 16 + c] = pack8(hf);
        unpack8(((const uint4*)Ebf)[(size_t)v * 16 + c], evf);
        #pragma unroll
        for (int j = 0; j < 8; ++j) eh[j] = evf[j] * hf[j];
        ((uint4*)EHb)[(size_t)v * 16 + c] = pack8(eh);
    }
}

// ---------------------------------------------------------------------------
// out = leaky(Hb @ W1b^T + b1) + leaky(EHb @ W2b^T + b2), 16x16x32 bf16 MFMA.
// ---------------------------------------------------------------------------
__global__ __launch_bounds__(256) void gemm_bf(
    const unsigned short* __restrict__ Hb, const unsigned short* __restrict__ EHb,
    const unsigned short* __restrict__ W1b, const unsigned short* __restrict__ W2b,
    const float* __restrict__ b1, const float* __restrict__ b2,
    float* __restrict__ out)
{
    const int wave = threadIdx.x >> 6;
    const int lane = threadIdx.x & 63;
    const int v0 = blockIdx.x * 64 + wave * 16;
    if (v0 >= NN) return;
    const int m = lane & 15;
    const int quad = lane >> 4;

    bf16x8 aH[4], aE[4];
    const unsigned short* hrow = Hb  + (size_t)(v0 + m) * DD + quad * 8;
    const unsigned short* erow = EHb + (size_t)(v0 + m) * DD + quad * 8;
    #pragma unroll
    for (int ks = 0; ks < 4; ++ks) {
        aH[ks] = *(const bf16x8*)(hrow + ks * 32);
        aE[ks] = *(const bf16x8*)(erow + ks * 32);
    }

    #pragma unroll
    for (int jt = 0; jt < 8; ++jt) {
        const int j0 = jt * 16;
        const unsigned short* w1r = W1b + (size_t)(j0 + m) * DD + quad * 8;
        const unsigned short* w2r = W2b + (size_t)(j0 + m) * DD + quad * 8;
        f32x4 acc1 = {0.f, 0.f, 0.f, 0.f}, acc2 = {0.f, 0.f, 0.f, 0.f};
        #pragma unroll
        for (int ks = 0; ks < 4; ++ks) {
            bf16x8 bw1 = *(const bf16x8*)(w1r + ks * 32);
            bf16x8 bw2 = *(const bf16x8*)(w2r + ks * 32);
            acc1 = __builtin_amdgcn_mfma_f32_16x16x32_bf16(aH[ks], bw1, acc1, 0, 0, 0);
            acc2 = __builtin_amdgcn_mfma_f32_16x16x32_bf16(aE[ks], bw2, acc2, 0, 0, 0);
        }
        const float bb1 = b1[j0 + m], bb2 = b2[j0 + m];
        #pragma unroll
        for (int i = 0; i < 4; ++i) {
            float x1 = acc1[i] + bb1; x1 = x1 > 0.f ? x1 : SLOPE * x1;
            float x2 = acc2[i] + bb2; x2 = x2 > 0.f ? x2 : SLOPE * x2;
            out[(size_t)(v0 + quad * 4 + i) * DD + j0 + m] = x1 + x2;
        }
    }
}

// ============== minimal fallback (ws too small): fp32 atomics ==============
__global__ __launch_bounds__(256) void scatter_add(
    const float* __restrict__ E, const int* __restrict__ src,
    const int* __restrict__ dst, float* __restrict__ H, int n_edges)
{
    int t = blockIdx.x * 256 + threadIdx.x;
    int e = t >> 5;
    if (e >= n_edges) return;
    int c = t & 31;
    float4 a = ((const float4*)E)[(size_t)src[e] * 32 + c];
    float* hp = H + (size_t)dst[e] * DD + c * 4;
    atomicAdd(hp + 0, a.x); atomicAdd(hp + 1, a.y);
    atomicAdd(hp + 2, a.z); atomicAdd(hp + 3, a.w);
}

__global__ __launch_bounds__(256) void fused_mlp(
    const float* __restrict__ E, const float* __restrict__ H,
    const float* __restrict__ W1, const float* __restrict__ b1,
    const float* __restrict__ W2, const float* __restrict__ b2,
    float* __restrict__ out)
{
    __shared__ float Hs[32][DD];
    __shared__ float EHs[32][DD];
    __shared__ float W1s[DD][20];
    __shared__ float W2s[DD][20];
    const int tid = threadIdx.x;
    const int v0 = blockIdx.x * 32;
    const int nvalid = min(32, NN - v0);
    for (int i = 0; i < 4; ++i) {
        int f = tid + 256 * i;
        int n = f >> 5, c = f & 31;
        float4 h = make_float4(0.f, 0.f, 0.f, 0.f);
        float4 eh = h;
        if (n < nvalid) {
            h = ((const float4*)H)[(size_t)(v0 + n) * 32 + c];
            float4 e4 = ((const float4*)E)[(size_t)(v0 + n) * 32 + c];
            eh = make_float4(e4.x * h.x, e4.y * h.y, e4.z * h.z, e4.w * h.w);
        }
        *((float4*)&Hs[n][c * 4]) = h;
        *((float4*)&EHs[n][c * 4]) = eh;
    }
    const int jg = tid & 63;
    const int n0 = (tid >> 6) * 8;
    float acc1a[8] = {}, acc1b[8] = {}, acc2a[8] = {}, acc2b[8] = {};
    for (int t8 = 0; t8 < 8; ++t8) {
        const int k0 = t8 * 16;
        __syncthreads();
        for (int i = 0; i < 8; ++i) {
            int f = tid + 256 * i;
            int j = f >> 4, kk = f & 15;
            W1s[j][kk] = W1[j * DD + k0 + kk];
            W2s[j][kk] = W2[j * DD + k0 + kk];
        }
        __syncthreads();
        for (int c = 0; c < 4; ++c) {
            float4 w1a = *((const float4*)&W1s[jg][c * 4]);
            float4 w1b = *((const float4*)&W1s[jg + 64][c * 4]);
            float4 w2a = *((const float4*)&W2s[jg][c * 4]);
            float4 w2b = *((const float4*)&W2s[jg + 64][c * 4]);
            const int kk = k0 + c * 4;
            for (int n = 0; n < 8; ++n) {
                float4 h = *((const float4*)&Hs[n0 + n][kk]);
                float4 eh = *((const float4*)&EHs[n0 + n][kk]);
                acc1a[n] += h.x * w1a.x + h.y * w1a.y + h.z * w1a.z + h.w * w1a.w;
                acc1b[n] += h.x * w1b.x + h.y * w1b.y + h.z * w1b.z + h.w * w1b.w;
                acc2a[n] += eh.x * w2a.x + eh.y * w2a.y + eh.z * w2a.z + eh.w * w2a.w;
                acc2b[n] += eh.x * w2b.x + eh.y * w2b.y + eh.z * w2b.z + eh.w * w2b.w;
            }
        }
    }
    const float b1a = b1[jg], b1b = b1[jg + 64];
    const float b2a = b2[jg], b2b = b2[jg + 64];
    for (int n = 0; n < 8; ++n) {
        if (n0 + n < nvalid) {
            const int v = v0 + n0 + n;
            float x1 = acc1a[n] + b1a; x1 = x1 > 0.f ? x1 : SLOPE * x1;
            float x2 = acc2a[n] + b2a; x2 = x2 > 0.f ? x2 : SLOPE * x2;
            out[(size_t)v * DD + jg] = x1 + x2;
            float y1 = acc1b[n] + b1b; y1 = y1 > 0.f ? y1 : SLOPE * y1;
            float y2 = acc2b[n] + b2b; y2 = y2 > 0.f ? y2 : SLOPE * y2;
            out[(size_t)v * DD + jg + 64] = y1 + y2;
        }
    }
}
// ===========================================================================

extern "C" void kernel_launch(void* const* d_in, const int* in_sizes, int n_in,
                              void* d_out, int out_size, void* d_ws, size_t ws_size,
                              hipStream_t stream)
{
    const float* E  = (const float*)d_in[0];
    const float* W1 = (const float*)d_in[1];
    const float* b1 = (const float*)d_in[2];
    const float* W2 = (const float*)d_in[3];
    const float* b2 = (const float*)d_in[4];
    const int* src  = (const int*)d_in[5];
    const int* dst  = (const int*)d_in[6];
    float* out = (float*)d_out;
    const int n_edges = in_sizes[5];

    char* ws = (char*)d_ws;
    auto al = [](size_t x) { return (x + 255) & ~(size_t)255; };

    const size_t off_tail = 0;                                  // NB*4
    const size_t off_ovfc = (size_t)NB * 4;
    const size_t off_ovf  = al(off_ovfc + 4);
    const size_t off_stag = al(off_ovf + (size_t)OVCAP * 8);
    const size_t off_Ebf  = al(off_stag + (size_t)NB * BCAP * 4);
    const size_t off_Hb   = al(off_Ebf + (size_t)NN * DD * 2);
    const size_t off_EHb  = al(off_Hb + (size_t)NN * DD * 2);
    const size_t off_W1b  = al(off_EHb + (size_t)NN * DD * 2);
    const size_t off_W2b  = al(off_W1b + (size_t)DD * DD * 2);
    const size_t need_bf  = off_W2b + (size_t)DD * DD * 2;      // ~47 MB

    if (ws_size >= need_bf) {
        int*  gtail   = (int*)(ws + off_tail);
        int*  ovf_cnt = (int*)(ws + off_ovfc);
        int2* ovf     = (int2*)(ws + off_ovf);
        unsigned int*   stag = (unsigned int*)(ws + off_stag);
        unsigned short* Ebf  = (unsigned short*)(ws + off_Ebf);
        unsigned short* Hb   = (unsigned short*)(ws + off_Hb);
        unsigned short* EHb  = (unsigned short*)(ws + off_EHb);
        unsigned short* W1b  = (unsigned short*)(ws + off_W1b);
        unsigned short* W2b  = (unsigned short*)(ws + off_W2b);

        hipMemsetAsync(ws, 0, off_ovf, stream);   // gtail + ovf_cnt
        const int ncv = NN * DD / 8 + 2 * (DD * DD / 8);
        convert_bf<<<(ncv + 255) / 256, 256, 0, stream>>>(E, W1, W2, Ebf, W1b, W2b);
        bin_sort<<<(n_edges + ECH - 1) / ECH, 256, 0, stream>>>(
            src, dst, gtail, stag, ovf_cnt, ovf, n_edges);
        bucket_gather<<<NB, 256, 0, stream>>>(Ebf, gtail, stag, Hb, EHb);
        fix_overflow_bf<<<1, 64, 0, stream>>>(ovf_cnt, ovf, Ebf, Hb, EHb);
        gemm_bf<<<(NN + 63) / 64, 256, 0, stream>>>(Hb, EHb, W1b, W2b, b1, b2, out);
        return;
    }

    // fallback: fp32 atomics into H (= ws if it fits, else out), then fused MLP
    const size_t hbytes = (size_t)NN * DD * sizeof(float);
    float* H = (ws_size >= hbytes) ? (float*)ws : out;
    hipMemsetAsync(H, 0, hbytes, stream);
    scatter_add<<<((n_edges * 32) + 255) / 256, 256, 0, stream>>>(
        E, src, dst, H, n_edges);
    fused_mlp<<<(NN + 31) / 32, 256, 0, stream>>>(E, H, W1, b1, W2, b2, out);
}

// Round 6
// 214.977 us; speedup vs baseline: 13.8329x; 1.0165x over previous
//
#include <hip/hip_runtime.h>

#define NN 50000
#define DD 128
#define SLOPE 0.01f
#define NB 782        // staging buckets of 64 nodes: bucket = v>>6
#define BCAP 2560     // per-bucket cap; mean 2046, sigma 45 -> +11 sigma
#define ECH 6144      // edges per bin_sort block -> 261 blocks (covers 256 CUs)
#define BST 512       // bin_sort block threads
#define PB 2          // buckets per thread in prefix scan (512*2 >= 782)
#define OVCAP 8192

using bf16x8 = __attribute__((ext_vector_type(8))) short;
using f32x4  = __attribute__((ext_vector_type(4))) float;

// ---------------- bf16 helpers (RNE) ----------------
__device__ inline float bflo(unsigned int w) { return __uint_as_float(w << 16); }
__device__ inline float bfhi(unsigned int w) { return __uint_as_float(w & 0xffff0000u); }
__device__ inline unsigned int rnebf(float f) {
    unsigned int u = __float_as_uint(f);
    return (u + 0x7fffu + ((u >> 16) & 1u)) >> 16;
}
__device__ inline unsigned int pack2(float lo, float hi) {
    return rnebf(lo) | (rnebf(hi) << 16);
}
__device__ inline void unpack8(uint4 r, float* f) {
    f[0] = bflo(r.x); f[1] = bfhi(r.x); f[2] = bflo(r.y); f[3] = bfhi(r.y);
    f[4] = bflo(r.z); f[5] = bfhi(r.z); f[6] = bflo(r.w); f[7] = bfhi(r.w);
}
__device__ inline uint4 pack8(const float* f) {
    uint4 o;
    o.x = pack2(f[0], f[1]); o.y = pack2(f[2], f[3]);
    o.z = pack2(f[4], f[5]); o.w = pack2(f[6], f[7]);
    return o;
}
__device__ inline void addrow(float* acc, uint4 r) {
    acc[0] += bflo(r.x); acc[1] += bfhi(r.x);
    acc[2] += bflo(r.y); acc[3] += bfhi(r.y);
    acc[4] += bflo(r.z); acc[5] += bfhi(r.z);
    acc[6] += bflo(r.w); acc[7] += bfhi(r.w);
}

// ---------------------------------------------------------------------------
// fp32 -> bf16 conversion of E, W1, W2.
// ---------------------------------------------------------------------------
__global__ __launch_bounds__(256) void convert_bf(
    const float* __restrict__ E, const float* __restrict__ W1,
    const float* __restrict__ W2, unsigned short* __restrict__ Ebf,
    unsigned short* __restrict__ W1b, unsigned short* __restrict__ W2b)
{
    const int NE8 = NN * DD / 8;
    const int NW8 = DD * DD / 8;
    int t = blockIdx.x * 256 + threadIdx.x;
    const float* s; unsigned short* d; int idx;
    if (t < NE8)                { s = E;  d = Ebf; idx = t; }
    else if (t < NE8 + NW8)     { s = W1; d = W1b; idx = t - NE8; }
    else if (t < NE8 + 2 * NW8) { s = W2; d = W2b; idx = t - NE8 - NW8; }
    else return;
    float4 a = ((const float4*)s)[(size_t)idx * 2];
    float4 b = ((const float4*)s)[(size_t)idx * 2 + 1];
    uint4 o;
    o.x = pack2(a.x, a.y); o.y = pack2(a.z, a.w);
    o.z = pack2(b.x, b.y); o.w = pack2(b.z, b.w);
    ((uint4*)d)[idx] = o;
}

// ---------------------------------------------------------------------------
// Block-local LDS counting sort of ECH edges by bucket (v>>6), then flush
// each bucket's run with ONE global atomicAdd + contiguous stores.
// Record: src (16b) | (v & 63) << 16.   512 threads, 261 blocks.
// ---------------------------------------------------------------------------
__global__ __launch_bounds__(BST) void bin_sort(
    const int* __restrict__ src, const int* __restrict__ dst,
    int* __restrict__ gtail, unsigned int* __restrict__ stag,
    int* __restrict__ ovf_cnt, int2* __restrict__ ovf, int n_edges)
{
    __shared__ unsigned int srt[ECH];     // 24 KB
    __shared__ int cnt[NB], off[NB], pos[NB];
    __shared__ int wsum[BST / 64];

    const int tid = threadIdx.x;
    const int e0 = blockIdx.x * ECH;
    const int m = min(ECH, n_edges - e0);

    for (int b = tid; b < NB; b += BST) cnt[b] = 0;
    __syncthreads();

    // pass 1: histogram (LDS atomics)
    for (int i = tid; i < m; i += BST)
        atomicAdd(&cnt[dst[e0 + i] >> 6], 1);
    __syncthreads();

    // exclusive prefix sum over NB: thread t covers buckets [PB*t, PB*t+PB)
    const int lane = tid & 63, w = tid >> 6;
    int b0 = tid * PB;
    int loc[PB]; int s = 0;
    #pragma unroll
    for (int j = 0; j < PB; ++j) {
        int bb = b0 + j;
        int cv = (bb < NB) ? cnt[bb] : 0;
        loc[j] = s; s += cv;
    }
    int incl = s;
    #pragma unroll
    for (int d = 1; d < 64; d <<= 1) {
        int t2 = __shfl_up(incl, d);
        if (lane >= d) incl += t2;
    }
    if (lane == 63) wsum[w] = incl;
    __syncthreads();
    int wbase = 0;
    for (int w2 = 0; w2 < w; ++w2) wbase += wsum[w2];
    int base = wbase + incl - s;
    #pragma unroll
    for (int j = 0; j < PB; ++j) {
        int bb = b0 + j;
        if (bb < NB) { off[bb] = base + loc[j]; pos[bb] = base + loc[j]; }
    }
    __syncthreads();

    // pass 2: place records into LDS-sorted order
    for (int i = tid; i < m; i += BST) {
        int v = dst[e0 + i];
        int u = src[e0 + i];
        int p = atomicAdd(&pos[v >> 6], 1);
        srt[p] = (unsigned int)u | ((unsigned int)(v & 63) << 16);
    }
    __syncthreads();

    // flush: one global atomic per nonempty bucket, contiguous run copy
    for (int bb = tid; bb < NB; bb += BST) {
        int c = cnt[bb];
        if (!c) continue;
        int g = atomicAdd(&gtail[bb], c);
        int s0 = off[bb];
        unsigned int* dstp = stag + (size_t)bb * BCAP;
        for (int k = 0; k < c; ++k) {
            int gp = g + k;
            unsigned int r = srt[s0 + k];
            if (gp < BCAP) {
                dstp[gp] = r;
            } else {
                int oi = atomicAdd(ovf_cnt, 1);
                if (oi < OVCAP)
                    ovf[oi] = make_int2((int)(r & 0xffffu),
                                        bb * 64 + (int)((r >> 16) & 63));
            }
        }
    }
}

// ---------------------------------------------------------------------------
// TWO blocks per staging bucket; each handles 32 of the 64 nodes. Both read
// the same segment (L2-hit for the second), counting-sort their half by
// node-low5 in LDS, then gather-sum E rows (8-deep load pipeline).
// ---------------------------------------------------------------------------
__global__ __launch_bounds__(256) void bucket_gather(
    const unsigned short* __restrict__ Ebf, const int* __restrict__ gtail,
    const unsigned int* __restrict__ stag, unsigned short* __restrict__ Hb,
    unsigned short* __restrict__ EHb)
{
    __shared__ unsigned short sorted[BCAP];   // 5 KB (worst case: all one half)
    __shared__ int cnt[32], off[33], pos[32];

    const int b = blockIdx.x >> 1;
    const int half = blockIdx.x & 1;
    const int tid = threadIdx.x;
    int len = gtail[b]; len = len < BCAP ? len : BCAP;
    const unsigned int* seg = stag + (size_t)b * BCAP;

    if (tid < 32) cnt[tid] = 0;
    __syncthreads();
    for (int i = tid; i < len; i += 256) {
        int nl = (seg[i] >> 16) & 63;
        if ((nl >> 5) == half) atomicAdd(&cnt[nl & 31], 1);
    }
    __syncthreads();
    if (tid == 0) {
        int a = 0;
        for (int j = 0; j < 32; ++j) { off[j] = a; pos[j] = a; a += cnt[j]; }
        off[32] = a;
    }
    __syncthreads();
    for (int i = tid; i < len; i += 256) {
        unsigned int r = seg[i];
        int nl = (r >> 16) & 63;
        if ((nl >> 5) == half) {
            int p = atomicAdd(&pos[nl & 31], 1);
            sorted[p] = (unsigned short)(r & 0xffffu);
        }
    }
    __syncthreads();

    // gather: 16 lanes per node x 16 nodes per pass, 2 passes
    const int g = tid >> 4;
    const int c = tid & 15;
    const uint4* E4 = (const uint4*)Ebf;
    for (int p2 = 0; p2 < 2; ++p2) {
        int nl = p2 * 16 + g;
        int v = b * 64 + half * 32 + nl;
        if (v >= NN) continue;
        float acc[8] = {};
        int i = off[nl], e1 = off[nl + 1];
        for (; i + 8 <= e1; i += 8) {       // 8 row-loads in flight
            uint4 r0 = E4[(size_t)sorted[i]     * 16 + c];
            uint4 r1 = E4[(size_t)sorted[i + 1] * 16 + c];
            uint4 r2 = E4[(size_t)sorted[i + 2] * 16 + c];
            uint4 r3 = E4[(size_t)sorted[i + 3] * 16 + c];
            uint4 r4 = E4[(size_t)sorted[i + 4] * 16 + c];
            uint4 r5 = E4[(size_t)sorted[i + 5] * 16 + c];
            uint4 r6 = E4[(size_t)sorted[i + 6] * 16 + c];
            uint4 r7 = E4[(size_t)sorted[i + 7] * 16 + c];
            addrow(acc, r0); addrow(acc, r1); addrow(acc, r2); addrow(acc, r3);
            addrow(acc, r4); addrow(acc, r5); addrow(acc, r6); addrow(acc, r7);
        }
        for (; i + 2 <= e1; i += 2) {
            uint4 r0 = E4[(size_t)sorted[i]     * 16 + c];
            uint4 r1 = E4[(size_t)sorted[i + 1] * 16 + c];
            addrow(acc, r0); addrow(acc, r1);
        }
        if (i < e1) addrow(acc, E4[(size_t)sorted[i] * 16 + c]);

        float ef[8]; unpack8(E4[(size_t)v * 16 + c], ef);
        float eh[8];
        #pragma unroll
        for (int j = 0; j < 8; ++j) eh[j] = ef[j] * acc[j];
        ((uint4*)Hb)[(size_t)v * 16 + c] = pack8(acc);
        ((uint4*)EHb)[(size_t)v * 16 + c] = pack8(eh);
    }
}

// Safety net for staging overflow (expected empty). Single wave, serial.
__global__ void fix_overflow_bf(
    const int* __restrict__ ovf_cnt, const int2* __restrict__ ovf,
    const unsigned short* __restrict__ Ebf, unsigned short* __restrict__ Hb,
    unsigned short* __restrict__ EHb)
{
    int total = *ovf_cnt; total = total < OVCAP ? total : OVCAP;
    if (total == 0) return;
    int c = threadIdx.x;
    if (c >= 16) return;
    for (int i = 0; i < total; ++i) {
        int u = ovf[i].x, v = ovf[i].y;
        float hf[8], ef[8], evf[8], eh[8];
        unpack8(((const uint4*)Hb)[(size_t)v * 16 + c], hf);
        unpack8(((const uint4*)Ebf)[(size_t)u * 16 + c], ef);
        #pragma unroll
        for (int j = 0; j < 8; ++j) hf[j] += ef[j];
        ((uint4*)Hb)[(size_t)v * 16 + c] = pack8(hf);
        unpack8(((const uint4*)Ebf)[(size_t)v * 16 + c], evf);
        #pragma unroll
        for (int j = 0; j < 8; ++j) eh[j] = evf[j] * hf[j];
        ((uint4*)EHb)[(size_t)v * 16 + c] = pack8(eh);
    }
}

// ---------------------------------------------------------------------------
// out = leaky(Hb @ W1b^T + b1) + leaky(EHb @ W2b^T + b2), 16x16x32 bf16 MFMA.
// ---------------------------------------------------------------------------
__global__ __launch_bounds__(256) void gemm_bf(
    const unsigned short* __restrict__ Hb, const unsigned short* __restrict__ EHb,
    const unsigned short* __restrict__ W1b, const unsigned short* __restrict__ W2b,
    const float* __restrict__ b1, const float* __restrict__ b2,
    float* __restrict__ out)
{
    const int wave = threadIdx.x >> 6;
    const int lane = threadIdx.x & 63;
    const int v0 = blockIdx.x * 64 + wave * 16;
    if (v0 >= NN) return;
    const int m = lane & 15;
    const int quad = lane >> 4;

    bf16x8 aH[4], aE[4];
    const unsigned short* hrow = Hb  + (size_t)(v0 + m) * DD + quad * 8;
    const unsigned short* erow = EHb + (size_t)(v0 + m) * DD + quad * 8;
    #pragma unroll
    for (int ks = 0; ks < 4; ++ks) {
        aH[ks] = *(const bf16x8*)(hrow + ks * 32);
        aE[ks] = *(const bf16x8*)(erow + ks * 32);
    }

    #pragma unroll
    for (int jt = 0; jt < 8; ++jt) {
        const int j0 = jt * 16;
        const unsigned short* w1r = W1b + (size_t)(j0 + m) * DD + quad * 8;
        const unsigned short* w2r = W2b + (size_t)(j0 + m) * DD + quad * 8;
        f32x4 acc1 = {0.f, 0.f, 0.f, 0.f}, acc2 = {0.f, 0.f, 0.f, 0.f};
        #pragma unroll
        for (int ks = 0; ks < 4; ++ks) {
            bf16x8 bw1 = *(const bf16x8*)(w1r + ks * 32);
            bf16x8 bw2 = *(const bf16x8*)(w2r + ks * 32);
            acc1 = __builtin_amdgcn_mfma_f32_16x16x32_bf16(aH[ks], bw1, acc1, 0, 0, 0);
            acc2 = __builtin_amdgcn_mfma_f32_16x16x32_bf16(aE[ks], bw2, acc2, 0, 0, 0);
        }
        const float bb1 = b1[j0 + m], bb2 = b2[j0 + m];
        #pragma unroll
        for (int i = 0; i < 4; ++i) {
            float x1 = acc1[i] + bb1; x1 = x1 > 0.f ? x1 : SLOPE * x1;
            float x2 = acc2[i] + bb2; x2 = x2 > 0.f ? x2 : SLOPE * x2;
            out[(size_t)(v0 + quad * 4 + i) * DD + j0 + m] = x1 + x2;
        }
    }
}

// ============== minimal fallback (ws too small): fp32 atomics ==============
__global__ __launch_bounds__(256) void scatter_add(
    const float* __restrict__ E, const int* __restrict__ src,
    const int* __restrict__ dst, float* __restrict__ H, int n_edges)
{
    int t = blockIdx.x * 256 + threadIdx.x;
    int e = t >> 5;
    if (e >= n_edges) return;
    int c = t & 31;
    float4 a = ((const float4*)E)[(size_t)src[e] * 32 + c];
    float* hp = H + (size_t)dst[e] * DD + c * 4;
    atomicAdd(hp + 0, a.x); atomicAdd(hp + 1, a.y);
    atomicAdd(hp + 2, a.z); atomicAdd(hp + 3, a.w);
}

__global__ __launch_bounds__(256) void fused_mlp(
    const float* __restrict__ E, const float* __restrict__ H,
    const float* __restrict__ W1, const float* __restrict__ b1,
    const float* __restrict__ W2, const float* __restrict__ b2,
    float* __restrict__ out)
{
    __shared__ float Hs[32][DD];
    __shared__ float EHs[32][DD];
    __shared__ float W1s[DD][20];
    __shared__ float W2s[DD][20];
    const int tid = threadIdx.x;
    const int v0 = blockIdx.x * 32;
    const int nvalid = min(32, NN - v0);
    for (int i = 0; i < 4; ++i) {
        int f = tid + 256 * i;
        int n = f >> 5, c = f & 31;
        float4 h = make_float4(0.f, 0.f, 0.f, 0.f);
        float4 eh = h;
        if (n < nvalid) {
            h = ((const float4*)H)[(size_t)(v0 + n) * 32 + c];
            float4 e4 = ((const float4*)E)[(size_t)(v0 + n) * 32 + c];
            eh = make_float4(e4.x * h.x, e4.y * h.y, e4.z * h.z, e4.w * h.w);
        }
        *((float4*)&Hs[n][c * 4]) = h;
        *((float4*)&EHs[n][c * 4]) = eh;
    }
    const int jg = tid & 63;
    const int n0 = (tid >> 6) * 8;
    float acc1a[8] = {}, acc1b[8] = {}, acc2a[8] = {}, acc2b[8] = {};
    for (int t8 = 0; t8 < 8; ++t8) {
        const int k0 = t8 * 16;
        __syncthreads();
        for (int i = 0; i < 8; ++i) {
            int f = tid + 256 * i;
            int j = f >> 4, kk = f & 15;
            W1s[j][kk] = W1[j * DD + k0 + kk];
            W2s[j][kk] = W2[j * DD + k0 + kk];
        }
        __syncthreads();
        for (int c = 0; c < 4; ++c) {
            float4 w1a = *((const float4*)&W1s[jg][c * 4]);
            float4 w1b = *((const float4*)&W1s[jg + 64][c * 4]);
            float4 w2a = *((const float4*)&W2s[jg][c * 4]);
            float4 w2b = *((const float4*)&W2s[jg + 64][c * 4]);
            const int kk = k0 + c * 4;
            for (int n = 0; n < 8; ++n) {
                float4 h = *((const float4*)&Hs[n0 + n][kk]);
                float4 eh = *((const float4*)&EHs[n0 + n][kk]);
                acc1a[n] += h.x * w1a.x + h.y * w1a.y + h.z * w1a.z + h.w * w1a.w;
                acc1b[n] += h.x * w1b.x + h.y * w1b.y + h.z * w1b.z + h.w * w1b.w;
                acc2a[n] += eh.x * w2a.x + eh.y * w2a.y + eh.z * w2a.z + eh.w * w2a.w;
                acc2b[n] += eh.x * w2b.x + eh.y * w2b.y + eh.z * w2b.z + eh.w * w2b.w;
            }
        }
    }
    const float b1a = b1[jg], b1b = b1[jg + 64];
    const float b2a = b2[jg], b2b = b2[jg + 64];
    for (int n = 0; n < 8; ++n) {
        if (n0 + n < nvalid) {
            const int v = v0 + n0 + n;
            float x1 = acc1a[n] + b1a; x1 = x1 > 0.f ? x1 : SLOPE * x1;
            float x2 = acc2a[n] + b2a; x2 = x2 > 0.f ? x2 : SLOPE * x2;
            out[(size_t)v * DD + jg] = x1 + x2;
            float y1 = acc1b[n] + b1b; y1 = y1 > 0.f ? y1 : SLOPE * y1;
            float y2 = acc2b[n] + b2b; y2 = y2 > 0.f ? y2 : SLOPE * y2;
            out[(size_t)v * DD + jg + 64] = y1 + y2;
        }
    }
}
// ===========================================================================

extern "C" void kernel_launch(void* const* d_in, const int* in_sizes, int n_in,
                              void* d_out, int out_size, void* d_ws, size_t ws_size,
                              hipStream_t stream)
{
    const float* E  = (const float*)d_in[0];
    const float* W1 = (const float*)d_in[1];
    const float* b1 = (const float*)d_in[2];
    const float* W2 = (const float*)d_in[3];
    const float* b2 = (const float*)d_in[4];
    const int* src  = (const int*)d_in[5];
    const int* dst  = (const int*)d_in[6];
    float* out = (float*)d_out;
    const int n_edges = in_sizes[5];

    char* ws = (char*)d_ws;
    auto al = [](size_t x) { return (x + 255) & ~(size_t)255; };

    const size_t off_tail = 0;                                  // NB*4
    const size_t off_ovfc = (size_t)NB * 4;
    const size_t off_ovf  = al(off_ovfc + 4);
    const size_t off_stag = al(off_ovf + (size_t)OVCAP * 8);
    const size_t off_Ebf  = al(off_stag + (size_t)NB * BCAP * 4);
    const size_t off_Hb   = al(off_Ebf + (size_t)NN * DD * 2);
    const size_t off_EHb  = al(off_Hb + (size_t)NN * DD * 2);
    const size_t off_W1b  = al(off_EHb + (size_t)NN * DD * 2);
    const size_t off_W2b  = al(off_W1b + (size_t)DD * DD * 2);
    const size_t need_bf  = off_W2b + (size_t)DD * DD * 2;      // ~47 MB

    if (ws_size >= need_bf) {
        int*  gtail   = (int*)(ws + off_tail);
        int*  ovf_cnt = (int*)(ws + off_ovfc);
        int2* ovf     = (int2*)(ws + off_ovf);
        unsigned int*   stag = (unsigned int*)(ws + off_stag);
        unsigned short* Ebf  = (unsigned short*)(ws + off_Ebf);
        unsigned short* Hb   = (unsigned short*)(ws + off_Hb);
        unsigned short* EHb  = (unsigned short*)(ws + off_EHb);
        unsigned short* W1b  = (unsigned short*)(ws + off_W1b);
        unsigned short* W2b  = (unsigned short*)(ws + off_W2b);

        hipMemsetAsync(ws, 0, off_ovf, stream);   // gtail + ovf_cnt
        const int ncv = NN * DD / 8 + 2 * (DD * DD / 8);
        convert_bf<<<(ncv + 255) / 256, 256, 0, stream>>>(E, W1, W2, Ebf, W1b, W2b);
        bin_sort<<<(n_edges + ECH - 1) / ECH, BST, 0, stream>>>(
            src, dst, gtail, stag, ovf_cnt, ovf, n_edges);
        bucket_gather<<<NB * 2, 256, 0, stream>>>(Ebf, gtail, stag, Hb, EHb);
        fix_overflow_bf<<<1, 64, 0, stream>>>(ovf_cnt, ovf, Ebf, Hb, EHb);
        gemm_bf<<<(NN + 63) / 64, 256, 0, stream>>>(Hb, EHb, W1b, W2b, b1, b2, out);
        return;
    }

    // fallback: fp32 atomics into H (= ws if it fits, else out), then fused MLP
    const size_t hbytes = (size_t)NN * DD * sizeof(float);
    float* H = (ws_size >= hbytes) ? (float*)ws : out;
    hipMemsetAsync(H, 0, hbytes, stream);
    scatter_add<<<((n_edges * 32) + 255) / 256, 256, 0, stream>>>(
        E, src, dst, H, n_edges);
    fused_mlp<<<(NN + 31) / 32, 256, 0, stream>>>(E, H, W1, b1, W2, b2, out);
}

// Round 7
// 197.369 us; speedup vs baseline: 15.0670x; 1.0892x over previous
//
#include <hip/hip_runtime.h>

#define NN 50000
#define DD 128
#define SLOPE 0.01f
#define NB 782        // buckets of 64 nodes: bucket = v>>6
#define BCAP 2560     // per-bucket cap; mean 2046, sigma 45 -> +11 sigma
#define ECH 6144      // edges per bin block
#define BST 512       // convert_bin block threads
#define PB 2          // buckets per thread in prefix scan (512*2 >= 782)
#define OVCAP 8192
#define HP 136        // Hs row pitch (bf16): 272B rows -> even b128 bank groups

using bf16x8 = __attribute__((ext_vector_type(8))) short;
using f32x4  = __attribute__((ext_vector_type(4))) float;

// ---------------- bf16 helpers (RNE) ----------------
__device__ inline float bflo(unsigned int w) { return __uint_as_float(w << 16); }
__device__ inline float bfhi(unsigned int w) { return __uint_as_float(w & 0xffff0000u); }
__device__ inline float sbf(short s) {
    return __uint_as_float(((unsigned int)(unsigned short)s) << 16);
}
__device__ inline unsigned int rnebf(float f) {
    unsigned int u = __float_as_uint(f);
    return (u + 0x7fffu + ((u >> 16) & 1u)) >> 16;
}
__device__ inline unsigned int pack2(float lo, float hi) {
    return rnebf(lo) | (rnebf(hi) << 16);
}
__device__ inline uint4 pack8(const float* f) {
    uint4 o;
    o.x = pack2(f[0], f[1]); o.y = pack2(f[2], f[3]);
    o.z = pack2(f[4], f[5]); o.w = pack2(f[6], f[7]);
    return o;
}
__device__ inline void addrow(float* acc, uint4 r) {
    acc[0] += bflo(r.x); acc[1] += bfhi(r.x);
    acc[2] += bflo(r.y); acc[3] += bfhi(r.y);
    acc[4] += bflo(r.z); acc[5] += bfhi(r.z);
    acc[6] += bflo(r.w); acc[7] += bfhi(r.w);
}

// ---------------------------------------------------------------------------
// Fused: blocks [0,nbin) do LDS counting-sort binning of ECH edges each;
// blocks [nbin,..) convert E/W1/W2 fp32->bf16. Independent work co-scheduled.
// ---------------------------------------------------------------------------
__global__ __launch_bounds__(BST) void convert_bin(
    const float* __restrict__ E, const float* __restrict__ W1,
    const float* __restrict__ W2, const int* __restrict__ src,
    const int* __restrict__ dst, unsigned short* __restrict__ Ebf,
    unsigned short* __restrict__ W1b, unsigned short* __restrict__ W2b,
    int* __restrict__ gtail, unsigned int* __restrict__ stag,
    int* __restrict__ ovf_cnt, int2* __restrict__ ovf,
    int n_edges, int nbin)
{
    const int tid = threadIdx.x;

    if (blockIdx.x >= nbin) {
        // ---------------- convert branch ----------------
        const int NE8 = NN * DD / 8;      // 800000
        const int NW8 = DD * DD / 8;      // 2048
        int t = (blockIdx.x - nbin) * BST + tid;
        const float* s; unsigned short* d; int idx;
        if (t < NE8)                { s = E;  d = Ebf; idx = t; }
        else if (t < NE8 + NW8)     { s = W1; d = W1b; idx = t - NE8; }
        else if (t < NE8 + 2 * NW8) { s = W2; d = W2b; idx = t - NE8 - NW8; }
        else return;
        float4 a = ((const float4*)s)[(size_t)idx * 2];
        float4 b = ((const float4*)s)[(size_t)idx * 2 + 1];
        uint4 o;
        o.x = pack2(a.x, a.y); o.y = pack2(a.z, a.w);
        o.z = pack2(b.x, b.y); o.w = pack2(b.z, b.w);
        ((uint4*)d)[idx] = o;
        return;
    }

    // ---------------- bin branch: LDS counting sort by bucket ----------------
    __shared__ unsigned int srt[ECH];     // 24 KB
    __shared__ int cnt[NB], off[NB], pos[NB];
    __shared__ int wsum[BST / 64];

    const int e0 = blockIdx.x * ECH;
    const int m = min(ECH, n_edges - e0);

    for (int b = tid; b < NB; b += BST) cnt[b] = 0;
    __syncthreads();

    for (int i = tid; i < m; i += BST)
        atomicAdd(&cnt[dst[e0 + i] >> 6], 1);
    __syncthreads();

    const int lane = tid & 63, w = tid >> 6;
    int b0 = tid * PB;
    int loc[PB]; int s = 0;
    #pragma unroll
    for (int j = 0; j < PB; ++j) {
        int bb = b0 + j;
        int cv = (bb < NB) ? cnt[bb] : 0;
        loc[j] = s; s += cv;
    }
    int incl = s;
    #pragma unroll
    for (int d = 1; d < 64; d <<= 1) {
        int t2 = __shfl_up(incl, d);
        if (lane >= d) incl += t2;
    }
    if (lane == 63) wsum[w] = incl;
    __syncthreads();
    int wbase = 0;
    for (int w2 = 0; w2 < w; ++w2) wbase += wsum[w2];
    int base = wbase + incl - s;
    #pragma unroll
    for (int j = 0; j < PB; ++j) {
        int bb = b0 + j;
        if (bb < NB) { off[bb] = base + loc[j]; pos[bb] = base + loc[j]; }
    }
    __syncthreads();

    for (int i = tid; i < m; i += BST) {
        int v = dst[e0 + i];
        int u = src[e0 + i];
        int p = atomicAdd(&pos[v >> 6], 1);
        srt[p] = (unsigned int)u | ((unsigned int)(v & 63) << 16);
    }
    __syncthreads();

    // flush: one global atomic per nonempty bucket, contiguous run copy
    for (int bb = tid; bb < NB; bb += BST) {
        int c = cnt[bb];
        if (!c) continue;
        int g = atomicAdd(&gtail[bb], c);
        int s0 = off[bb];
        unsigned int* dstp = stag + (size_t)bb * BCAP;
        for (int k = 0; k < c; ++k) {
            int gp = g + k;
            unsigned int r = srt[s0 + k];
            if (gp < BCAP) {
                dstp[gp] = r;
            } else {
                int oi = atomicAdd(ovf_cnt, 1);
                if (oi < OVCAP)
                    ovf[oi] = make_int2((int)(r & 0xffffu),
                                        bb * 64 + (int)((r >> 16) & 63));
            }
        }
    }
}

// ---------------------------------------------------------------------------
// Fused gather + GEMM. One block per bucket (64 nodes):
//   A) counting-sort the bucket's records by node-low6 in LDS
//   B) gather-sum E rows per node (8-deep load pipeline), fold any overflow
//      edges, store H rows as bf16 in LDS (pitch HP -> conflict-free b128)
//   C) 4 waves: wave w does the 16x16x32-MFMA GEMM for rows w*16..w*16+15,
//      EH A-frags rebuilt in-register from Hs * Ebf[v]; fused leaky epilogue.
// ---------------------------------------------------------------------------
__global__ __launch_bounds__(256) void bucket_fused(
    const unsigned short* __restrict__ Ebf, const int* __restrict__ gtail,
    const unsigned int* __restrict__ stag, const int* __restrict__ ovf_cnt,
    const int2* __restrict__ ovf,
    const unsigned short* __restrict__ W1b, const unsigned short* __restrict__ W2b,
    const float* __restrict__ b1, const float* __restrict__ b2,
    float* __restrict__ out)
{
    __shared__ unsigned short sorted[BCAP];       // 5 KB
    __shared__ unsigned short Hs[64][HP];         // 17 KB
    __shared__ int cnt[64], off[65], pos[64];
    __shared__ int s_novf;

    const int b = blockIdx.x;
    const int tid = threadIdx.x;
    int len = gtail[b]; len = len < BCAP ? len : BCAP;
    const unsigned int* seg = stag + (size_t)b * BCAP;

    if (tid == 0) { int t = *ovf_cnt; s_novf = t < OVCAP ? t : OVCAP; }
    if (tid < 64) cnt[tid] = 0;
    __syncthreads();
    for (int i = tid; i < len; i += 256)
        atomicAdd(&cnt[(seg[i] >> 16) & 63], 1);
    __syncthreads();
    if (tid == 0) {
        int a = 0;
        for (int j = 0; j < 64; ++j) { off[j] = a; pos[j] = a; a += cnt[j]; }
        off[64] = a;
    }
    __syncthreads();
    for (int i = tid; i < len; i += 256) {
        unsigned int r = seg[i];
        int p = atomicAdd(&pos[(r >> 16) & 63], 1);
        sorted[p] = (unsigned short)(r & 0xffffu);
    }
    __syncthreads();
    const int novf = s_novf;

    // ---- gather: 16 lanes per node x 16 nodes per pass, 4 passes ----
    const int g = tid >> 4;
    const int c = tid & 15;
    const uint4* E4 = (const uint4*)Ebf;
    for (int p4 = 0; p4 < 4; ++p4) {
        int nl = p4 * 16 + g;
        int v = b * 64 + nl;
        if (v >= NN) continue;
        float acc[8] = {};
        int i = off[nl], e1 = off[nl + 1];
        for (; i + 8 <= e1; i += 8) {
            uint4 r0 = E4[(size_t)sorted[i]     * 16 + c];
            uint4 r1 = E4[(size_t)sorted[i + 1] * 16 + c];
            uint4 r2 = E4[(size_t)sorted[i + 2] * 16 + c];
            uint4 r3 = E4[(size_t)sorted[i + 3] * 16 + c];
            uint4 r4 = E4[(size_t)sorted[i + 4] * 16 + c];
            uint4 r5 = E4[(size_t)sorted[i + 5] * 16 + c];
            uint4 r6 = E4[(size_t)sorted[i + 6] * 16 + c];
            uint4 r7 = E4[(size_t)sorted[i + 7] * 16 + c];
            addrow(acc, r0); addrow(acc, r1); addrow(acc, r2); addrow(acc, r3);
            addrow(acc, r4); addrow(acc, r5); addrow(acc, r6); addrow(acc, r7);
        }
        for (; i + 2 <= e1; i += 2) {
            uint4 r0 = E4[(size_t)sorted[i]     * 16 + c];
            uint4 r1 = E4[(size_t)sorted[i + 1] * 16 + c];
            addrow(acc, r0); addrow(acc, r1);
        }
        if (i < e1) addrow(acc, E4[(size_t)sorted[i] * 16 + c]);

        if (novf > 0) {                    // rare path: fold overflow edges
            for (int k = 0; k < novf; ++k) {
                int2 e = ovf[k];
                if (e.y == v) addrow(acc, E4[(size_t)e.x * 16 + c]);
            }
        }
        *(uint4*)&Hs[nl][c * 8] = pack8(acc);
    }
    __syncthreads();

    // ---- GEMM: wave w -> node rows w*16 .. w*16+15 ----
    const int wave = tid >> 6;
    const int lane = tid & 63;
    const int v0 = b * 64 + wave * 16;
    if (v0 >= NN) return;                 // only trailing waves of last bucket
    const int m = lane & 15;
    const int quad = lane >> 4;

    bf16x8 aH[4], aE[4];
    const unsigned short* hrow = &Hs[wave * 16 + m][quad * 8];
    const unsigned short* erow = Ebf + (size_t)(v0 + m) * DD + quad * 8;
    #pragma unroll
    for (int ks = 0; ks < 4; ++ks) {
        bf16x8 h8 = *(const bf16x8*)(hrow + ks * 32);
        bf16x8 e8 = *(const bf16x8*)(erow + ks * 32);
        aH[ks] = h8;
        bf16x8 eh;
        #pragma unroll
        for (int j = 0; j < 8; ++j)
            eh[j] = (short)rnebf(sbf(h8[j]) * sbf(e8[j]));
        aE[ks] = eh;
    }

    #pragma unroll
    for (int jt = 0; jt < 8; ++jt) {
        const int j0 = jt * 16;
        const unsigned short* w1r = W1b + (size_t)(j0 + m) * DD + quad * 8;
        const unsigned short* w2r = W2b + (size_t)(j0 + m) * DD + quad * 8;
        f32x4 acc1 = {0.f, 0.f, 0.f, 0.f}, acc2 = {0.f, 0.f, 0.f, 0.f};
        #pragma unroll
        for (int ks = 0; ks < 4; ++ks) {
            bf16x8 bw1 = *(const bf16x8*)(w1r + ks * 32);
            bf16x8 bw2 = *(const bf16x8*)(w2r + ks * 32);
            acc1 = __builtin_amdgcn_mfma_f32_16x16x32_bf16(aH[ks], bw1, acc1, 0, 0, 0);
            acc2 = __builtin_amdgcn_mfma_f32_16x16x32_bf16(aE[ks], bw2, acc2, 0, 0, 0);
        }
        const float bb1 = b1[j0 + m], bb2 = b2[j0 + m];
        #pragma unroll
        for (int i = 0; i < 4; ++i) {
            int row = v0 + quad * 4 + i;
            if (row < NN) {
                float x1 = acc1[i] + bb1; x1 = x1 > 0.f ? x1 : SLOPE * x1;
                float x2 = acc2[i] + bb2; x2 = x2 > 0.f ? x2 : SLOPE * x2;
                out[(size_t)row * DD + j0 + m] = x1 + x2;
            }
        }
    }
}

// ============== minimal fallback (ws too small): fp32 atomics ==============
__global__ __launch_bounds__(256) void scatter_add(
    const float* __restrict__ E, const int* __restrict__ src,
    const int* __restrict__ dst, float* __restrict__ H, int n_edges)
{
    int t = blockIdx.x * 256 + threadIdx.x;
    int e = t >> 5;
    if (e >= n_edges) return;
    int c = t & 31;
    float4 a = ((const float4*)E)[(size_t)src[e] * 32 + c];
    float* hp = H + (size_t)dst[e] * DD + c * 4;
    atomicAdd(hp + 0, a.x); atomicAdd(hp + 1, a.y);
    atomicAdd(hp + 2, a.z); atomicAdd(hp + 3, a.w);
}

__global__ __launch_bounds__(256) void fused_mlp(
    const float* __restrict__ E, const float* __restrict__ H,
    const float* __restrict__ W1, const float* __restrict__ b1,
    const float* __restrict__ W2, const float* __restrict__ b2,
    float* __restrict__ out)
{
    __shared__ float Hsf[32][DD];
    __shared__ float EHs[32][DD];
    __shared__ float W1s[DD][20];
    __shared__ float W2s[DD][20];
    const int tid = threadIdx.x;
    const int v0 = blockIdx.x * 32;
    const int nvalid = min(32, NN - v0);
    for (int i = 0; i < 4; ++i) {
        int f = tid + 256 * i;
        int n = f >> 5, c = f & 31;
        float4 h = make_float4(0.f, 0.f, 0.f, 0.f);
        float4 eh = h;
        if (n < nvalid) {
            h = ((const float4*)H)[(size_t)(v0 + n) * 32 + c];
            float4 e4 = ((const float4*)E)[(size_t)(v0 + n) * 32 + c];
            eh = make_float4(e4.x * h.x, e4.y * h.y, e4.z * h.z, e4.w * h.w);
        }
        *((float4*)&Hsf[n][c * 4]) = h;
        *((float4*)&EHs[n][c * 4]) = eh;
    }
    const int jg = tid & 63;
    const int n0 = (tid >> 6) * 8;
    float acc1a[8] = {}, acc1b[8] = {}, acc2a[8] = {}, acc2b[8] = {};
    for (int t8 = 0; t8 < 8; ++t8) {
        const int k0 = t8 * 16;
        __syncthreads();
        for (int i = 0; i < 8; ++i) {
            int f = tid + 256 * i;
            int j = f >> 4, kk = f & 15;
            W1s[j][kk] = W1[j * DD + k0 + kk];
            W2s[j][kk] = W2[j * DD + k0 + kk];
        }
        __syncthreads();
        for (int c = 0; c < 4; ++c) {
            float4 w1a = *((const float4*)&W1s[jg][c * 4]);
            float4 w1b = *((const float4*)&W1s[jg + 64][c * 4]);
            float4 w2a = *((const float4*)&W2s[jg][c * 4]);
            float4 w2b = *((const float4*)&W2s[jg + 64][c * 4]);
            const int kk = k0 + c * 4;
            for (int n = 0; n < 8; ++n) {
                float4 h = *((const float4*)&Hsf[n0 + n][kk]);
                float4 eh = *((const float4*)&EHs[n0 + n][kk]);
                acc1a[n] += h.x * w1a.x + h.y * w1a.y + h.z * w1a.z + h.w * w1a.w;
                acc1b[n] += h.x * w1b.x + h.y * w1b.y + h.z * w1b.z + h.w * w1b.w;
                acc2a[n] += eh.x * w2a.x + eh.y * w2a.y + eh.z * w2a.z + eh.w * w2a.w;
                acc2b[n] += eh.x * w2b.x + eh.y * w2b.y + eh.z * w2b.z + eh.w * w2b.w;
            }
        }
    }
    const float b1a = b1[jg], b1b = b1[jg + 64];
    const float b2a = b2[jg], b2b = b2[jg + 64];
    for (int n = 0; n < 8; ++n) {
        if (n0 + n < nvalid) {
            const int v = v0 + n0 + n;
            float x1 = acc1a[n] + b1a; x1 = x1 > 0.f ? x1 : SLOPE * x1;
            float x2 = acc2a[n] + b2a; x2 = x2 > 0.f ? x2 : SLOPE * x2;
            out[(size_t)v * DD + jg] = x1 + x2;
            float y1 = acc1b[n] + b1b; y1 = y1 > 0.f ? y1 : SLOPE * y1;
            float y2 = acc2b[n] + b2b; y2 = y2 > 0.f ? y2 : SLOPE * y2;
            out[(size_t)v * DD + jg + 64] = y1 + y2;
        }
    }
}
// ===========================================================================

extern "C" void kernel_launch(void* const* d_in, const int* in_sizes, int n_in,
                              void* d_out, int out_size, void* d_ws, size_t ws_size,
                              hipStream_t stream)
{
    const float* E  = (const float*)d_in[0];
    const float* W1 = (const float*)d_in[1];
    const float* b1 = (const float*)d_in[2];
    const float* W2 = (const float*)d_in[3];
    const float* b2 = (const float*)d_in[4];
    const int* src  = (const int*)d_in[5];
    const int* dst  = (const int*)d_in[6];
    float* out = (float*)d_out;
    const int n_edges = in_sizes[5];

    char* ws = (char*)d_ws;
    auto al = [](size_t x) { return (x + 255) & ~(size_t)255; };

    const size_t off_tail = 0;                                  // NB*4
    const size_t off_ovfc = (size_t)NB * 4;
    const size_t off_ovf  = al(off_ovfc + 4);
    const size_t off_stag = al(off_ovf + (size_t)OVCAP * 8);
    const size_t off_Ebf  = al(off_stag + (size_t)NB * BCAP * 4);
    const size_t off_W1b  = al(off_Ebf + (size_t)NN * DD * 2);
    const size_t off_W2b  = al(off_W1b + (size_t)DD * DD * 2);
    const size_t need_bf  = off_W2b + (size_t)DD * DD * 2;      // ~21 MB

    if (ws_size >= need_bf) {
        int*  gtail   = (int*)(ws + off_tail);
        int*  ovf_cnt = (int*)(ws + off_ovfc);
        int2* ovf     = (int2*)(ws + off_ovf);
        unsigned int*   stag = (unsigned int*)(ws + off_stag);
        unsigned short* Ebf  = (unsigned short*)(ws + off_Ebf);
        unsigned short* W1b  = (unsigned short*)(ws + off_W1b);
        unsigned short* W2b  = (unsigned short*)(ws + off_W2b);

        const int nbin = (n_edges + ECH - 1) / ECH;
        const int ncv  = NN * DD / 8 + 2 * (DD * DD / 8);
        const int ncvb = (ncv + BST - 1) / BST;

        hipMemsetAsync(ws, 0, off_ovf, stream);   // gtail + ovf_cnt
        convert_bin<<<nbin + ncvb, BST, 0, stream>>>(
            E, W1, W2, src, dst, Ebf, W1b, W2b,
            gtail, stag, ovf_cnt, ovf, n_edges, nbin);
        bucket_fused<<<NB, 256, 0, stream>>>(
            Ebf, gtail, stag, ovf_cnt, ovf, W1b, W2b, b1, b2, out);
        return;
    }

    // fallback: fp32 atomics into H (= ws if it fits, else out), then fused MLP
    const size_t hbytes = (size_t)NN * DD * sizeof(float);
    float* H = (ws_size >= hbytes) ? (float*)ws : out;
    hipMemsetAsync(H, 0, hbytes, stream);
    scatter_add<<<((n_edges * 32) + 255) / 256, 256, 0, stream>>>(
        E, src, dst, H, n_edges);
    fused_mlp<<<(NN + 31) / 32, 256, 0, stream>>>(E, H, W1, b1, W2, b2, out);
}